// Round 12
// baseline (1657.207 us; speedup 1.0000x reference)
//
#include <hip/hip_runtime.h>
#include <hip/hip_bf16.h>
#include <math.h>

typedef __hip_bfloat16 bf16;
typedef unsigned short u16;
typedef unsigned int u32;
typedef __attribute__((ext_vector_type(8))) short short8;
typedef __attribute__((ext_vector_type(4))) float f32x4;
typedef __attribute__((ext_vector_type(2))) float f32x2;

#define BATCH 4
#define NNODE 10000
#define TLEN 128
#define NEDGE 160000
#define GDIM 256
#define NHEAD 4

// small-weight fp32 staging offsets (everything except W0/W1/Wa1/Wc1)
#define S_CW1 0
#define S_CB1 96
#define S_CB2 128
#define S_AS0 192
#define S_AD0 448
#define S_B0  704
#define S_AS1 960
#define S_AD1 1216
#define S_B1  1472
#define S_BC1 1728
#define S_WC2 1856
#define S_BC2 2112
#define S_BA1 2114
#define S_WA2 2178
#define S_BA2 2242
#define S_TOTAL 2243

__device__ __forceinline__ float prelu(float v) { return 0.5f * (v + fabsf(v)); }
__device__ __forceinline__ u16 f2b(float f) {
    union { float f; u32 u; } v; v.f = f;
    u32 r = v.u + 0x7FFF + ((v.u >> 16) & 1);
    return (u16)(r >> 16);
}
__device__ __forceinline__ float u2f(u16 u) {
    union { u32 u; float f; } v; v.u = ((u32)u) << 16;
    return v.f;
}
__device__ __forceinline__ float ldw(const void* p, int off, bool isbf) {
    return isbf ? u2f(((const u16*)p)[off]) : ((const float*)p)[off];
}

// per-wave inline dtype probes (all waves compute identical results)
__device__ __forceinline__ bool probe_x_bf16(const void* xsrc) {
    int lane = threadIdx.x & 63;
    u16 h = ((const u16*)xsrc)[2 * lane];
    int e = (h >> 7) & 0xFF;
    unsigned long long m = __ballot(e >= 117 && e <= 130);
    return __popcll(m) >= 32;
}
__device__ __forceinline__ bool probe_ei64(const int* ei) {
    int lane = threadIdx.x & 63;
    int v = ei[2 * lane + 1];
    unsigned long long m = __ballot(v == 0);
    return __popcll(m) >= 56;
}

struct WPtrs { const void* p[20]; };

// ------ merged: bf16 transposes + dst histogram + small-weight fp32 staging ------
#define PRE_TBLK 665   // covers max(65536, 170000) indices
__global__ __launch_bounds__(256) void k_pre(WPtrs wp, const void* __restrict__ xsrc,
        const int* __restrict__ ei, float* __restrict__ wbuf,
        u16* __restrict__ cw2r, u16* __restrict__ W0t, u16* __restrict__ W1t,
        u16* __restrict__ Wa1t, int* __restrict__ counts) {
    bool isbf = probe_x_bf16(xsrc);
    int b = blockIdx.x;
    if (b >= PRE_TBLK) {   // small-weight staging (9 blocks)
        const int C2[16] = {0,96,128,192,448,704,960,1216,1472,1728,1856,2112,
                            2114,2178,2242,2243};
        const int SRC[15] = {0,1,3,5,6,7,9,10,11,13,14,15,17,18,19};
        int i = (b - PRE_TBLK) * 256 + threadIdx.x;
        if (i >= S_TOTAL) return;
        int j = 14;
        for (int t = 0; t < 15; ++t) { if (i < C2[t + 1]) { j = t; break; } }
        wbuf[i] = ldw(wp.p[SRC[j]], i - C2[j], isbf);
        return;
    }
    int i = b * 256 + threadIdx.x;
    if (i < 6144) {   // cw2r[c2][k'=dk*32+ci]
        int c2 = i / 96, k = i - c2 * 96, s = k >> 5, ci = k & 31;
        cw2r[i] = f2b(ldw(wp.p[2], c2 * 96 + ci * 3 + s, isbf));
    }
    if (i < 16384) {  // W0t / Wa1t, coalesced reads
        int k = i >> 8, c = i & 255;
        W0t[c * 64 + k] = f2b(ldw(wp.p[4], k * 256 + c, isbf));
        int ka = i >> 6, ca = i & 63;
        Wa1t[ca * 256 + ka] = f2b(ldw(wp.p[16], ka * 64 + ca, isbf));
    }
    if (i < 65536) {  // W1t
        int k = i >> 8, c = i & 255;
        W1t[c * 256 + k] = f2b(ldw(wp.p[8], k * 256 + c, isbf));
    }
    if (i < NEDGE + NNODE) {   // dst histogram (counts pre-zeroed by memset)
        bool ei64 = probe_ei64(ei);
        int dst;
        if (i < NEDGE) dst = ei64 ? ei[2 * (NEDGE + i)] : ei[NEDGE + i];
        else dst = i - NEDGE;
        if (dst >= 0 && dst < NNODE) atomicAdd(&counts[dst], 1);
    }
}

// ---------------- parallel scan ----------------
__global__ __launch_bounds__(256) void k_scan1(const int* __restrict__ counts,
        int* __restrict__ cur, int* __restrict__ bsum) {
    __shared__ int buf[256];
    int tid = threadIdx.x;
    int i = blockIdx.x * 256 + tid;
    int v = (i < NNODE) ? counts[i] : 0;
    buf[tid] = v;
    __syncthreads();
    for (int off = 1; off < 256; off <<= 1) {
        int t = (tid >= off) ? buf[tid - off] : 0;
        __syncthreads();
        buf[tid] += t;
        __syncthreads();
    }
    if (i < NNODE) cur[i] = buf[tid];
    if (tid == 255) bsum[blockIdx.x] = buf[255];
}
__global__ __launch_bounds__(256) void k_scan3(const int* __restrict__ counts,
        int* __restrict__ cur, const int* __restrict__ bsum, int* __restrict__ row_ptr) {
    __shared__ int pre_s;
    int tid = threadIdx.x;
    if (tid == 0) {
        int s = 0;
        for (int j = 0; j < blockIdx.x; ++j) s += bsum[j];
        pre_s = s;
    }
    __syncthreads();
    int i = blockIdx.x * 256 + tid;
    if (i >= NNODE) return;
    int incl = cur[i] + pre_s;
    row_ptr[i + 1] = incl;
    cur[i] = incl - counts[i];
    if (i == 0) row_ptr[0] = 0;
}

// ---------------- CSR fill ----------------
__global__ void k_fill(const int* __restrict__ ei,
                       int* __restrict__ cur, int* __restrict__ col_src) {
    bool ei64 = probe_ei64(ei);
    int e = blockIdx.x * 256 + threadIdx.x;
    if (e >= NEDGE + NNODE) return;
    int src, dst;
    if (e < NEDGE) {
        if (ei64) { src = ei[2 * e]; dst = ei[2 * (NEDGE + e)]; }
        else      { src = ei[e];     dst = ei[NEDGE + e]; }
    } else {
        src = dst = e - NEDGE;
    }
    if (dst < 0 || dst >= NNODE) return;
    int pos = atomicAdd(&cur[dst], 1);
    if (pos >= 0 && pos < NEDGE + NNODE) col_src[pos] = src;
}

// ---------------- fused temporal conv: R8 structure, HSTR 40, WSTR 96 ---------
#define HSTR 40
#define WSTR 96
__global__ __launch_bounds__(256) void k_conv(const void* __restrict__ xsrc,
        const float* __restrict__ wbuf, const u16* __restrict__ cw2r,
        u16* __restrict__ featb) {
    __shared__ __align__(16) float xs[4][132];
    __shared__ float w1s[96], b1s[32], b2s[64];
    __shared__ __align__(16) u16 w2s[64 * WSTR];
    __shared__ __align__(16) u16 hs[66 * HSTR];
    __shared__ float red2[4][64];

    bool isbf = probe_x_bf16(xsrc);
    int tid = threadIdx.x;
    int wave = tid >> 6, lane = tid & 63;
    int node0 = blockIdx.x * 4;

    {
        int j = tid >> 6, p = (tid & 63) * 2;
        if (isbf) {
            u32 w = ((const u32*)xsrc)[(size_t)node0 * 64 + tid];
            xs[j][1 + p] = u2f((u16)(w & 0xFFFF));
            xs[j][2 + p] = u2f((u16)(w >> 16));
        } else {
            float2 w = ((const float2*)xsrc)[(size_t)node0 * 64 + tid];
            xs[j][1 + p] = w.x;
            xs[j][2 + p] = w.y;
        }
    }
    if (tid < 8) xs[tid >> 1][(tid & 1) ? 129 : 0] = 0.f;
    if (tid < 96) w1s[tid] = wbuf[S_CW1 + tid];
    if (tid < 32) b1s[tid] = wbuf[S_CB1 + tid];
    if (tid < 64) b2s[tid] = wbuf[S_CB2 + tid];
    for (int i = tid; i < 768; i += 256)
        ((short8*)w2s)[i] = ((const short8*)cw2r)[i];   // identity: WSTR == 96
    if (tid < 32) hs[tid] = 0;
    else if (tid < 64) hs[65 * HSTR + (tid - 32)] = 0;
    __syncthreads();

    int d = tid & 15, uu = tid >> 4;
    float wa0 = w1s[6 * d + 0], wa1 = w1s[6 * d + 1], wa2 = w1s[6 * d + 2];
    float wb0 = w1s[6 * d + 3], wb1 = w1s[6 * d + 4], wb2 = w1s[6 * d + 5];
    float ba = b1s[2 * d], bb = b1s[2 * d + 1];
    int m = lane & 15, q = lane >> 4;
    int trow = wave * 16 + m;

    for (int j = 0; j < 4; ++j) {
        const float* xr = &xs[j][0];
        #pragma unroll
        for (int it = 0; it < 4; ++it) {
            int u = uu + 16 * it;
            int t0 = 2 * u;
            float x0 = xr[t0], x1 = xr[t0 + 1], x2 = xr[t0 + 2], x3 = xr[t0 + 3];
            f32x2 A = {x0, x1}, Bv = {x1, x2}, Cv = {x2, x3};
            f32x2 va = {ba, ba}; va += wa0 * A; va += wa1 * Bv; va += wa2 * Cv;
            f32x2 vb = {bb, bb}; vb += wb0 * A; vb += wb1 * Bv; vb += wb2 * Cv;
            float ha = fmaxf(fmaxf(va.x, va.y), 0.f);
            float hb = fmaxf(fmaxf(vb.x, vb.y), 0.f);
            __hip_bfloat162 hp2 = __float22bfloat162_rn(make_float2(ha, hb));
            u32 pack; __builtin_memcpy(&pack, &hp2, 4);
            *(u32*)&hs[(u + 1) * HSTR + 2 * d] = pack;
        }
        __syncthreads();

        short8 afr[3];
        #pragma unroll
        for (int s = 0; s < 3; ++s)
            afr[s] = *(const short8*)&hs[(trow + s) * HSTR + q * 8];
        float psum[4];
        #pragma unroll
        for (int nt = 0; nt < 4; ++nt) {
            int n = nt * 16 + m;
            f32x4 acc = {0.f, 0.f, 0.f, 0.f};
            #pragma unroll
            for (int s = 0; s < 3; ++s) {
                short8 bfr = *(const short8*)&w2s[n * WSTR + s * 32 + q * 8];
                acc = __builtin_amdgcn_mfma_f32_16x16x32_bf16(afr[s], bfr, acc, 0, 0, 0);
            }
            float b2v = b2s[n];
            float scl = prelu(acc[0] + b2v) + prelu(acc[1] + b2v)
                      + prelu(acc[2] + b2v) + prelu(acc[3] + b2v);
            scl += __shfl_xor(scl, 16, 64);
            scl += __shfl_xor(scl, 32, 64);
            psum[nt] = scl;
        }
        if (lane < 16) {
            #pragma unroll
            for (int nt = 0; nt < 4; ++nt)
                red2[wave][nt * 16 + lane] = psum[nt];
        }
        __syncthreads();
        if (tid < 64) {
            float tot = (red2[0][tid] + red2[1][tid] + red2[2][tid] + red2[3][tid]) * (1.f / 64.f);
            int node = node0 + j;
            int bb2 = node / NNODE, nn = node - bb2 * NNODE;
            featb[((size_t)nn * 4 + bb2) * 64 + tid] = f2b(tot);
        }
    }
}

// ------ zero-LDS MFMA GEMM (MT=1), fused attention scores ------
template<int K>
__global__ __launch_bounds__(256) void k_gemm(const u16* __restrict__ A,
        const u16* __restrict__ Wt, const float* __restrict__ att_s_w,
        const float* __restrict__ att_d_w, u16* __restrict__ outb,
        float* __restrict__ a_s, float* __restrict__ a_d) {
    int wave = threadIdx.x >> 6, lane = threadIdx.x & 63;
    int row0 = (blockIdx.x * 4 + wave) * 16;
    int m = lane & 15, q = lane >> 4;
    f32x4 acc[16];
    #pragma unroll
    for (int nt = 0; nt < 16; ++nt) acc[nt] = {0.f, 0.f, 0.f, 0.f};
    for (int kc = 0; kc < K; kc += 32) {
        short8 a = *(const short8*)&A[(size_t)(row0 + m) * K + kc + q * 8];
        #pragma unroll
        for (int nt = 0; nt < 16; ++nt) {
            short8 b = *(const short8*)&Wt[(size_t)(nt * 16 + m) * K + kc + q * 8];
            acc[nt] = __builtin_amdgcn_mfma_f32_16x16x32_bf16(a, b, acc[nt], 0, 0, 0);
        }
    }
    #pragma unroll
    for (int nt = 0; nt < 16; ++nt) {
        #pragma unroll
        for (int r = 0; r < 4; ++r)
            outb[(size_t)(row0 + q * 4 + r) * 256 + nt * 16 + m] = f2b(acc[nt][r]);
    }
    float sh_s[4][4] = {{0}}, sh_d[4][4] = {{0}};
    #pragma unroll
    for (int nt = 0; nt < 16; ++nt) {
        int h = nt >> 2;
        int cc = (nt & 3) * 16 + m;
        float asw = att_s_w[h * 64 + cc];
        float adw = att_d_w[h * 64 + cc];
        #pragma unroll
        for (int r = 0; r < 4; ++r) {
            sh_s[h][r] += acc[nt][r] * asw;
            sh_d[h][r] += acc[nt][r] * adw;
        }
    }
    #pragma unroll
    for (int off = 1; off < 16; off <<= 1) {
        #pragma unroll
        for (int h = 0; h < 4; ++h)
            #pragma unroll
            for (int r = 0; r < 4; ++r) {
                sh_s[h][r] += __shfl_xor(sh_s[h][r], off, 64);
                sh_d[h][r] += __shfl_xor(sh_d[h][r], off, 64);
            }
    }
    if (m == 0) {
        #pragma unroll
        for (int r = 0; r < 4; ++r) {
            int row = row0 + q * 4 + r;
            float4 vs = {sh_s[0][r], sh_s[1][r], sh_s[2][r], sh_s[3][r]};
            float4 vd = {sh_d[0][r], sh_d[1][r], sh_d[2][r], sh_d[3][r]};
            *(float4*)&a_s[(size_t)row * 4] = vs;
            *(float4*)&a_d[(size_t)row * 4] = vd;
        }
    }
}

// ---------------- GAT aggregation: depth-2 prefetch pipeline ----------------
template<int LAYER>
__global__ __launch_bounds__(256) void k_agg(const u16* __restrict__ xlb,
        const float* __restrict__ a_s, const float* __restrict__ a_d,
        const int* __restrict__ row_ptr, const int* __restrict__ col_src,
        const float* __restrict__ bias, u16* __restrict__ gb_out) {
    int wave = threadIdx.x >> 6, lane = threadIdx.x & 63;
    int dst = blockIdx.x * 2 + (wave >> 1);
    int bp = (wave & 1) * 2;
    int beg = row_ptr[dst], end = row_ptr[dst + 1];

    // pass 1: exact max per (b,h); 8-way edge split across replica groups
    int c = lane & 7, g = lane >> 3;
    int bc = bp + (c >> 2), hc = c & 3;
    float adv1 = a_d[(size_t)dst * 16 + bc * 4 + hc];
    float mloc = -INFINITY;
    for (int i = beg + g; i < end; i += 8) {
        int src = min(max(col_src[i], 0), NNODE - 1);
        float e = a_s[(size_t)src * 16 + bc * 4 + hc] + adv1;
        e = (e >= 0.f) ? e : 0.2f * e;
        mloc = fmaxf(mloc, e);
    }
    mloc = fmaxf(mloc, __shfl_xor(mloc, 8, 64));
    mloc = fmaxf(mloc, __shfl_xor(mloc, 16, 64));
    mloc = fmaxf(mloc, __shfl_xor(mloc, 32, 64));

    int bl = lane >> 5;
    int s = lane & 31;
    int h = s >> 3;
    int b = bp + bl;
    float mv = __shfl(mloc, bl * 4 + h, 64);

    // pass 2: depth-2 prefetch; 1 exp + 1x16B gather + 8 FMAs per edge
    float advh = a_d[(size_t)dst * 16 + b * 4 + h];
    float acc[8];
    #pragma unroll
    for (int k = 0; k < 8; ++k) acc[k] = 0.f;
    float l = 0.f;

    float asb[2] = {0.f, 0.f};
    short8 xb[2] = {{0}, {0}};
    #pragma unroll
    for (int d2 = 0; d2 < 2; ++d2) {
        int idx = beg + d2;
        if (idx < end) {
            int src = min(max(col_src[idx], 0), NNODE - 1);
            asb[d2] = a_s[(size_t)src * 16 + b * 4 + h];
            xb[d2] = *(const short8*)&xlb[((size_t)src * 4 + b) * 256 + s * 8];
        }
    }
    int slot = 0;
    for (int i = beg; i < end; ++i) {
        float e = asb[slot] + advh;
        e = (e >= 0.f) ? e : 0.2f * e;
        float p = __expf(e - mv);
        l += p;
        short8 xv = xb[slot];
        int ipre = i + 2;
        if (ipre < end) {
            int src = min(max(col_src[ipre], 0), NNODE - 1);
            asb[slot] = a_s[(size_t)src * 16 + b * 4 + h];
            xb[slot] = *(const short8*)&xlb[((size_t)src * 4 + b) * 256 + s * 8];
        }
        #pragma unroll
        for (int k = 0; k < 8; ++k) acc[k] += p * u2f((u16)xv[k]);
        slot ^= 1;
    }
    float rl = 1.f / (l + 1e-16f);
    short8 o;
    #pragma unroll
    for (int k = 0; k < 8; ++k)
        o[k] = (short)f2b(prelu(acc[k] * rl + bias[s * 8 + k]));
    *(short8*)&gb_out[((size_t)dst * 4 + b) * 256 + s * 8] = o;
}

// ---------------- attribution head (blocks <625) + pooled sum (blocks >=625) ----------
__global__ __launch_bounds__(256) void k_attrpool(const u16* __restrict__ gb,
        const u16* __restrict__ Wa1t, const float* __restrict__ wbuf,
        float* __restrict__ out, float* __restrict__ pooled) {
    if (blockIdx.x >= 625) {   // pool part
        int pb = blockIdx.x - 625;
        int b = pb >> 6;
        int chunk = pb & 63;
        int cch = threadIdx.x;
        int n0 = chunk * 157;
        int n1 = min(NNODE, n0 + 157);
        float acc = 0.f;
        for (int n = n0; n < n1; ++n)
            acc += u2f(gb[((size_t)n * 4 + b) * 256 + cch]);
        atomicAdd(&pooled[b * 256 + cch], acc);
        return;
    }
    int wave = threadIdx.x >> 6, lane = threadIdx.x & 63;
    int row0 = (blockIdx.x * 4 + wave) * 16;
    int m = lane & 15, q = lane >> 4;
    f32x4 acc[4];
    #pragma unroll
    for (int nt = 0; nt < 4; ++nt) acc[nt] = {0.f, 0.f, 0.f, 0.f};
    for (int kc = 0; kc < 256; kc += 32) {
        short8 a = *(const short8*)&gb[(size_t)(row0 + m) * 256 + kc + q * 8];
        #pragma unroll
        for (int nt = 0; nt < 4; ++nt) {
            short8 b = *(const short8*)&Wa1t[(size_t)(nt * 16 + m) * 256 + kc + q * 8];
            acc[nt] = __builtin_amdgcn_mfma_f32_16x16x32_bf16(a, b, acc[nt], 0, 0, 0);
        }
    }
    float part[4] = {0, 0, 0, 0};
    #pragma unroll
    for (int nt = 0; nt < 4; ++nt) {
        int col = nt * 16 + m;
        float ba1v = wbuf[S_BA1 + col];
        float wa2v = wbuf[S_WA2 + col];
        #pragma unroll
        for (int r = 0; r < 4; ++r)
            part[r] += prelu(acc[nt][r] + ba1v) * wa2v;
    }
    #pragma unroll
    for (int off = 1; off < 16; off <<= 1) {
        #pragma unroll
        for (int r = 0; r < 4; ++r)
            part[r] += __shfl_xor(part[r], off, 64);
    }
    if (m == 0) {
        float ba2v = wbuf[S_BA2];
        #pragma unroll
        for (int r = 0; r < 4; ++r) {
            int row = row0 + q * 4 + r;
            int n = row >> 2, b = row & 3;
            float v = part[r] + ba2v;
            out[8 + b * NNODE + n] = 1.f / (1.f + __expf(-v));
        }
    }
}

// ---------------- classification head (blocks 0-3) + diagnostics (block 4) ----------
__global__ __launch_bounds__(128) void k_logits(const float* __restrict__ pooled,
        const float* __restrict__ wbuf, const void* __restrict__ Wc1p,
        float* __restrict__ out,
        const u16* __restrict__ featb, const u16* __restrict__ gb,
        const int* __restrict__ row_ptr, const int* __restrict__ ei,
        const void* __restrict__ xsrc, int hostbad) {
    int tid = threadIdx.x;
    bool isbf = probe_x_bf16(xsrc);
    if (blockIdx.x == 4) {   // sampled diagnostics
        __shared__ float red[128];
        bool ei64 = probe_ei64(ei);
        float mx[2] = {0.f, 0.f};
        const u16* bufs[2] = {featb, gb};
        for (int qq = 0; qq < 2; ++qq) {
            const u16* p = bufs[qq];
            float m = 0.f;
            for (int i = tid; i < 2048; i += 128) {
                float v = u2f(p[i]);
                if (v != v) m = 1e30f;
                m = fmaxf(m, fabsf(v));
            }
            red[tid] = m;
            __syncthreads();
            for (int s2 = 64; s2 > 0; s2 >>= 1) {
                if (tid < s2) red[tid] = fmaxf(red[tid], red[tid + s2]);
                __syncthreads();
            }
            mx[qq] = red[0];
            __syncthreads();
        }
        if (tid == 0) {
            int fb = (mx[0] > 1e8f || mx[0] < 1e-6f) ? 1 : 0;
            int gbad = (mx[1] > 1e8f || mx[1] < 1e-6f) ? 1 : 0;
            int cb = (row_ptr[NNODE] != NEDGE + NNODE) ? 1 : 0;
            int code = 100 * fb + 400 * gbad + 800 * cb + 6400 * hostbad;
            if (code) {
                code += 1600 * (isbf ? 0 : 1);
                code += 3200 * (ei64 ? 1 : 0);
                for (int j = 0; j < 8; ++j) out[j] = (float)code;
            }
        }
        return;
    }
    __shared__ float pm[256];
    __shared__ float red4[4];
    int b = blockIdx.x;
    pm[tid] = pooled[b * 256 + tid] * (1.f / NNODE);
    pm[tid + 128] = pooled[b * 256 + tid + 128] * (1.f / NNODE);
    __syncthreads();
    float acc = wbuf[S_BC1 + tid];
    if (isbf) {
        const u16* w = (const u16*)Wc1p;
        #pragma unroll 4
        for (int k = 0; k < 256; ++k)
            acc += pm[k] * u2f(w[k * 128 + tid]);
    } else {
        const float* w = (const float*)Wc1p;
        #pragma unroll 4
        for (int k = 0; k < 256; ++k)
            acc += pm[k] * w[k * 128 + tid];
    }
    float hv = prelu(acc);
    float p0 = hv * wbuf[S_WC2 + tid * 2];
    float p1 = hv * wbuf[S_WC2 + tid * 2 + 1];
    #pragma unroll
    for (int off = 32; off > 0; off >>= 1) {
        p0 += __shfl_xor(p0, off, 64);
        p1 += __shfl_xor(p1, off, 64);
    }
    int wv = tid >> 6, lane = tid & 63;
    if (lane == 0) { red4[wv * 2] = p0; red4[wv * 2 + 1] = p1; }
    __syncthreads();
    if (tid < 2)
        out[b * 2 + tid] = red4[tid] + red4[2 + tid] + wbuf[S_BC2 + tid];
}

extern "C" void kernel_launch(void* const* d_in, const int* in_sizes, int n_in,
                              void* d_out, int out_size, void* d_ws, size_t ws_size,
                              hipStream_t stream) {
    const void* x  = d_in[0];
    const int*  ei = (const int*)d_in[1];
    float* out = (float*)d_out;

    WPtrs wp;
    for (int j = 0; j < 20; ++j) wp.p[j] = d_in[j + 2];

    char* ws = (char*)d_ws;
    size_t off = 0;
    auto alloc = [&](size_t bytes) -> void* {
        void* p = ws + off;
        off += (bytes + 255) & ~(size_t)255;
        return p;
    };
    float* wbuf    = (float*)alloc((size_t)S_TOTAL * 4);
    u16*   featb   = (u16*)  alloc((size_t)BATCH * NNODE * 64 * 2);
    u16*   xlb     = (u16*)  alloc((size_t)BATCH * NNODE * 256 * 2);
    u16*   gb      = (u16*)  alloc((size_t)BATCH * NNODE * 256 * 2);
    float* a_s     = (float*)alloc((size_t)BATCH * NNODE * 4 * 4);
    float* a_d     = (float*)alloc((size_t)BATCH * NNODE * 4 * 4);
    u16*   cw2r    = (u16*)alloc(6144 * 2);
    u16*   W0t     = (u16*)alloc(16384 * 2);
    u16*   W1t     = (u16*)alloc(65536 * 2);
    u16*   Wa1t    = (u16*)alloc(16384 * 2);
    // counts and pooled ADJACENT: one memset zeroes both
    int*   counts  = (int*)alloc(NNODE * 4);           // padded to 40192
    float* pooled  = (float*)alloc(BATCH * 256 * 4);   // 4096
    int*   row_ptr = (int*)alloc((NNODE + 1) * 4);
    int*   cur     = (int*)alloc(NNODE * 4);
    int*   col_src = (int*)alloc((NEDGE + NNODE) * 4);
    int*   bsum    = (int*)alloc(64 * 4);
    (void)ws_size; (void)out_size;

    int hostbad = (n_in != 22 || in_sizes[0] != BATCH * NNODE * TLEN ||
                   in_sizes[1] != 2 * NEDGE) ? 1 : 0;

    int eg = (NEDGE + NNODE + 255) / 256;

    hipMemsetAsync(counts, 0, 40192 + 4096, stream);

    k_pre<<<PRE_TBLK + 9, 256, 0, stream>>>(wp, x, ei, wbuf, cw2r, W0t, W1t, Wa1t, counts);
    k_scan1<<<40, 256, 0, stream>>>(counts, cur, bsum);
    k_scan3<<<40, 256, 0, stream>>>(counts, cur, bsum, row_ptr);
    k_fill<<<eg, 256, 0, stream>>>(ei, cur, col_src);

    k_conv<<<BATCH * NNODE / 4, 256, 0, stream>>>(x, wbuf, cw2r, featb);

    // GAT layer 0
    k_gemm<64><<<BATCH * NNODE / 64, 256, 0, stream>>>(featb, W0t,
            wbuf + S_AS0, wbuf + S_AD0, xlb, a_s, a_d);
    k_agg<0><<<NNODE / 2, 256, 0, stream>>>(xlb, a_s, a_d, row_ptr, col_src, wbuf + S_B0, gb);

    // GAT layer 1 (MT=1: 625 blocks for latency hiding)
    k_gemm<256><<<BATCH * NNODE / 64, 256, 0, stream>>>(gb, W1t,
            wbuf + S_AS1, wbuf + S_AD1, xlb, a_s, a_d);
    k_agg<1><<<NNODE / 2, 256, 0, stream>>>(xlb, a_s, a_d, row_ptr, col_src, wbuf + S_B1, gb);

    // heads
    k_attrpool<<<625 + 256, 256, 0, stream>>>(gb, Wa1t, wbuf, out, pooled);
    k_logits<<<5, 128, 0, stream>>>(pooled, wbuf, wp.p[12], out, featb, gb, row_ptr, ei, x, hostbad);
}

// Round 13
// 473.220 us; speedup vs baseline: 3.5020x; 3.5020x over previous
//
#include <hip/hip_runtime.h>
#include <hip/hip_bf16.h>
#include <math.h>

typedef __hip_bfloat16 bf16;
typedef unsigned short u16;
typedef unsigned int u32;
typedef __attribute__((ext_vector_type(8))) short short8;
typedef __attribute__((ext_vector_type(4))) float f32x4;
typedef __attribute__((ext_vector_type(2))) float f32x2;

#define BATCH 4
#define NNODE 10000
#define TLEN 128
#define NEDGE 160000
#define GDIM 256
#define NHEAD 4

// small-weight fp32 staging offsets (everything except W0/W1/Wa1/Wc1)
#define S_CW1 0
#define S_CB1 96
#define S_CB2 128
#define S_AS0 192
#define S_AD0 448
#define S_B0  704
#define S_AS1 960
#define S_AD1 1216
#define S_B1  1472
#define S_BC1 1728
#define S_WC2 1856
#define S_BC2 2112
#define S_BA1 2114
#define S_WA2 2178
#define S_BA2 2242
#define S_TOTAL 2243

__device__ __forceinline__ float prelu(float v) { return 0.5f * (v + fabsf(v)); }
__device__ __forceinline__ u16 f2b(float f) {
    union { float f; u32 u; } v; v.f = f;
    u32 r = v.u + 0x7FFF + ((v.u >> 16) & 1);
    return (u16)(r >> 16);
}
__device__ __forceinline__ float u2f(u16 u) {
    union { u32 u; float f; } v; v.u = ((u32)u) << 16;
    return v.f;
}
__device__ __forceinline__ float ldw(const void* p, int off, bool isbf) {
    return isbf ? u2f(((const u16*)p)[off]) : ((const float*)p)[off];
}

// per-wave inline dtype probes (all waves compute identical results)
__device__ __forceinline__ bool probe_x_bf16(const void* xsrc) {
    int lane = threadIdx.x & 63;
    u16 h = ((const u16*)xsrc)[2 * lane];
    int e = (h >> 7) & 0xFF;
    unsigned long long m = __ballot(e >= 117 && e <= 130);
    return __popcll(m) >= 32;
}
__device__ __forceinline__ bool probe_ei64(const int* ei) {
    int lane = threadIdx.x & 63;
    int v = ei[2 * lane + 1];
    unsigned long long m = __ballot(v == 0);
    return __popcll(m) >= 56;
}

struct WPtrs { const void* p[20]; };

// ------ merged: bf16 transposes + dst histogram + small-weight fp32 staging ------
#define PRE_TBLK 665   // covers max(65536, 170000) indices
__global__ __launch_bounds__(256) void k_pre(WPtrs wp, const void* __restrict__ xsrc,
        const int* __restrict__ ei, float* __restrict__ wbuf,
        u16* __restrict__ cw2r, u16* __restrict__ W0t, u16* __restrict__ W1t,
        u16* __restrict__ Wa1t, int* __restrict__ counts) {
    bool isbf = probe_x_bf16(xsrc);
    int b = blockIdx.x;
    if (b >= PRE_TBLK) {   // small-weight staging (9 blocks)
        const int C2[16] = {0,96,128,192,448,704,960,1216,1472,1728,1856,2112,
                            2114,2178,2242,2243};
        const int SRC[15] = {0,1,3,5,6,7,9,10,11,13,14,15,17,18,19};
        int i = (b - PRE_TBLK) * 256 + threadIdx.x;
        if (i >= S_TOTAL) return;
        int j = 14;
        for (int t = 0; t < 15; ++t) { if (i < C2[t + 1]) { j = t; break; } }
        wbuf[i] = ldw(wp.p[SRC[j]], i - C2[j], isbf);
        return;
    }
    int i = b * 256 + threadIdx.x;
    if (i < 6144) {   // cw2r[c2][k'=dk*32+ci]
        int c2 = i / 96, k = i - c2 * 96, s = k >> 5, ci = k & 31;
        cw2r[i] = f2b(ldw(wp.p[2], c2 * 96 + ci * 3 + s, isbf));
    }
    if (i < 16384) {  // W0t / Wa1t, coalesced reads
        int k = i >> 8, c = i & 255;
        W0t[c * 64 + k] = f2b(ldw(wp.p[4], k * 256 + c, isbf));
        int ka = i >> 6, ca = i & 63;
        Wa1t[ca * 256 + ka] = f2b(ldw(wp.p[16], ka * 64 + ca, isbf));
    }
    if (i < 65536) {  // W1t
        int k = i >> 8, c = i & 255;
        W1t[c * 256 + k] = f2b(ldw(wp.p[8], k * 256 + c, isbf));
    }
    if (i < NEDGE + NNODE) {   // dst histogram (counts pre-zeroed by memset)
        bool ei64 = probe_ei64(ei);
        int dst;
        if (i < NEDGE) dst = ei64 ? ei[2 * (NEDGE + i)] : ei[NEDGE + i];
        else dst = i - NEDGE;
        if (dst >= 0 && dst < NNODE) atomicAdd(&counts[dst], 1);
    }
}

// ---------------- parallel scan ----------------
__global__ __launch_bounds__(256) void k_scan1(const int* __restrict__ counts,
        int* __restrict__ cur, int* __restrict__ bsum) {
    __shared__ int buf[256];
    int tid = threadIdx.x;
    int i = blockIdx.x * 256 + tid;
    int v = (i < NNODE) ? counts[i] : 0;
    buf[tid] = v;
    __syncthreads();
    for (int off = 1; off < 256; off <<= 1) {
        int t = (tid >= off) ? buf[tid - off] : 0;
        __syncthreads();
        buf[tid] += t;
        __syncthreads();
    }
    if (i < NNODE) cur[i] = buf[tid];
    if (tid == 255) bsum[blockIdx.x] = buf[255];
}
__global__ __launch_bounds__(256) void k_scan3(const int* __restrict__ counts,
        int* __restrict__ cur, const int* __restrict__ bsum, int* __restrict__ row_ptr) {
    __shared__ int pre_s;
    int tid = threadIdx.x;
    if (tid == 0) {
        int s = 0;
        for (int j = 0; j < blockIdx.x; ++j) s += bsum[j];
        pre_s = s;
    }
    __syncthreads();
    int i = blockIdx.x * 256 + tid;
    if (i >= NNODE) return;
    int incl = cur[i] + pre_s;
    row_ptr[i + 1] = incl;
    cur[i] = incl - counts[i];
    if (i == 0) row_ptr[0] = 0;
}

// ---------------- CSR fill ----------------
__global__ void k_fill(const int* __restrict__ ei,
                       int* __restrict__ cur, int* __restrict__ col_src) {
    bool ei64 = probe_ei64(ei);
    int e = blockIdx.x * 256 + threadIdx.x;
    if (e >= NEDGE + NNODE) return;
    int src, dst;
    if (e < NEDGE) {
        if (ei64) { src = ei[2 * e]; dst = ei[2 * (NEDGE + e)]; }
        else      { src = ei[e];     dst = ei[NEDGE + e]; }
    } else {
        src = dst = e - NEDGE;
    }
    if (dst < 0 || dst >= NNODE) return;
    int pos = atomicAdd(&cur[dst], 1);
    if (pos >= 0 && pos < NEDGE + NNODE) col_src[pos] = src;
}

// ---------------- fused temporal conv: R8 structure, HSTR 40, WSTR 96 ---------
#define HSTR 40
#define WSTR 96
__global__ __launch_bounds__(256) void k_conv(const void* __restrict__ xsrc,
        const float* __restrict__ wbuf, const u16* __restrict__ cw2r,
        u16* __restrict__ featb) {
    __shared__ __align__(16) float xs[4][132];
    __shared__ float w1s[96], b1s[32], b2s[64];
    __shared__ __align__(16) u16 w2s[64 * WSTR];
    __shared__ __align__(16) u16 hs[66 * HSTR];
    __shared__ float red2[4][64];

    bool isbf = probe_x_bf16(xsrc);
    int tid = threadIdx.x;
    int wave = tid >> 6, lane = tid & 63;
    int node0 = blockIdx.x * 4;

    {
        int j = tid >> 6, p = (tid & 63) * 2;
        if (isbf) {
            u32 w = ((const u32*)xsrc)[(size_t)node0 * 64 + tid];
            xs[j][1 + p] = u2f((u16)(w & 0xFFFF));
            xs[j][2 + p] = u2f((u16)(w >> 16));
        } else {
            float2 w = ((const float2*)xsrc)[(size_t)node0 * 64 + tid];
            xs[j][1 + p] = w.x;
            xs[j][2 + p] = w.y;
        }
    }
    if (tid < 8) xs[tid >> 1][(tid & 1) ? 129 : 0] = 0.f;
    if (tid < 96) w1s[tid] = wbuf[S_CW1 + tid];
    if (tid < 32) b1s[tid] = wbuf[S_CB1 + tid];
    if (tid < 64) b2s[tid] = wbuf[S_CB2 + tid];
    for (int i = tid; i < 768; i += 256)
        ((short8*)w2s)[i] = ((const short8*)cw2r)[i];   // identity: WSTR == 96
    if (tid < 32) hs[tid] = 0;
    else if (tid < 64) hs[65 * HSTR + (tid - 32)] = 0;
    __syncthreads();

    int d = tid & 15, uu = tid >> 4;
    float wa0 = w1s[6 * d + 0], wa1 = w1s[6 * d + 1], wa2 = w1s[6 * d + 2];
    float wb0 = w1s[6 * d + 3], wb1 = w1s[6 * d + 4], wb2 = w1s[6 * d + 5];
    float ba = b1s[2 * d], bb = b1s[2 * d + 1];
    int m = lane & 15, q = lane >> 4;
    int trow = wave * 16 + m;

    for (int j = 0; j < 4; ++j) {
        const float* xr = &xs[j][0];
        #pragma unroll
        for (int it = 0; it < 4; ++it) {
            int u = uu + 16 * it;
            int t0 = 2 * u;
            float x0 = xr[t0], x1 = xr[t0 + 1], x2 = xr[t0 + 2], x3 = xr[t0 + 3];
            f32x2 A = {x0, x1}, Bv = {x1, x2}, Cv = {x2, x3};
            f32x2 va = {ba, ba}; va += wa0 * A; va += wa1 * Bv; va += wa2 * Cv;
            f32x2 vb = {bb, bb}; vb += wb0 * A; vb += wb1 * Bv; vb += wb2 * Cv;
            float ha = fmaxf(fmaxf(va.x, va.y), 0.f);
            float hb = fmaxf(fmaxf(vb.x, vb.y), 0.f);
            __hip_bfloat162 hp2 = __float22bfloat162_rn(make_float2(ha, hb));
            u32 pack; __builtin_memcpy(&pack, &hp2, 4);
            *(u32*)&hs[(u + 1) * HSTR + 2 * d] = pack;
        }
        __syncthreads();

        short8 afr[3];
        #pragma unroll
        for (int s = 0; s < 3; ++s)
            afr[s] = *(const short8*)&hs[(trow + s) * HSTR + q * 8];
        float psum[4];
        #pragma unroll
        for (int nt = 0; nt < 4; ++nt) {
            int n = nt * 16 + m;
            f32x4 acc = {0.f, 0.f, 0.f, 0.f};
            #pragma unroll
            for (int s = 0; s < 3; ++s) {
                short8 bfr = *(const short8*)&w2s[n * WSTR + s * 32 + q * 8];
                acc = __builtin_amdgcn_mfma_f32_16x16x32_bf16(afr[s], bfr, acc, 0, 0, 0);
            }
            float b2v = b2s[n];
            float scl = prelu(acc[0] + b2v) + prelu(acc[1] + b2v)
                      + prelu(acc[2] + b2v) + prelu(acc[3] + b2v);
            scl += __shfl_xor(scl, 16, 64);
            scl += __shfl_xor(scl, 32, 64);
            psum[nt] = scl;
        }
        if (lane < 16) {
            #pragma unroll
            for (int nt = 0; nt < 4; ++nt)
                red2[wave][nt * 16 + lane] = psum[nt];
        }
        __syncthreads();
        if (tid < 64) {
            float tot = (red2[0][tid] + red2[1][tid] + red2[2][tid] + red2[3][tid]) * (1.f / 64.f);
            int node = node0 + j;
            int bb2 = node / NNODE, nn = node - bb2 * NNODE;
            featb[((size_t)nn * 4 + bb2) * 64 + tid] = f2b(tot);
        }
    }
}

// ------ zero-LDS MFMA GEMM (MT=1), fused attention scores ------
template<int K>
__global__ __launch_bounds__(256) void k_gemm(const u16* __restrict__ A,
        const u16* __restrict__ Wt, const float* __restrict__ att_s_w,
        const float* __restrict__ att_d_w, u16* __restrict__ outb,
        float* __restrict__ a_s, float* __restrict__ a_d) {
    int wave = threadIdx.x >> 6, lane = threadIdx.x & 63;
    int row0 = (blockIdx.x * 4 + wave) * 16;
    int m = lane & 15, q = lane >> 4;
    f32x4 acc[16];
    #pragma unroll
    for (int nt = 0; nt < 16; ++nt) acc[nt] = {0.f, 0.f, 0.f, 0.f};
    for (int kc = 0; kc < K; kc += 32) {
        short8 a = *(const short8*)&A[(size_t)(row0 + m) * K + kc + q * 8];
        #pragma unroll
        for (int nt = 0; nt < 16; ++nt) {
            short8 b = *(const short8*)&Wt[(size_t)(nt * 16 + m) * K + kc + q * 8];
            acc[nt] = __builtin_amdgcn_mfma_f32_16x16x32_bf16(a, b, acc[nt], 0, 0, 0);
        }
    }
    #pragma unroll
    for (int nt = 0; nt < 16; ++nt) {
        #pragma unroll
        for (int r = 0; r < 4; ++r)
            outb[(size_t)(row0 + q * 4 + r) * 256 + nt * 16 + m] = f2b(acc[nt][r]);
    }
    float sh_s[4][4] = {{0}}, sh_d[4][4] = {{0}};
    #pragma unroll
    for (int nt = 0; nt < 16; ++nt) {
        int h = nt >> 2;
        int cc = (nt & 3) * 16 + m;
        float asw = att_s_w[h * 64 + cc];
        float adw = att_d_w[h * 64 + cc];
        #pragma unroll
        for (int r = 0; r < 4; ++r) {
            sh_s[h][r] += acc[nt][r] * asw;
            sh_d[h][r] += acc[nt][r] * adw;
        }
    }
    #pragma unroll
    for (int off = 1; off < 16; off <<= 1) {
        #pragma unroll
        for (int h = 0; h < 4; ++h)
            #pragma unroll
            for (int r = 0; r < 4; ++r) {
                sh_s[h][r] += __shfl_xor(sh_s[h][r], off, 64);
                sh_d[h][r] += __shfl_xor(sh_d[h][r], off, 64);
            }
    }
    if (m == 0) {
        #pragma unroll
        for (int r = 0; r < 4; ++r) {
            int row = row0 + q * 4 + r;
            float4 vs = {sh_s[0][r], sh_s[1][r], sh_s[2][r], sh_s[3][r]};
            float4 vd = {sh_d[0][r], sh_d[1][r], sh_d[2][r], sh_d[3][r]};
            *(float4*)&a_s[(size_t)row * 4] = vs;
            *(float4*)&a_d[(size_t)row * 4] = vd;
        }
    }
}

// ---------------- GAT aggregation: R11-proven depth-1 prefetch (NAMED scalars only;
// dynamic-indexed register arrays spill to scratch — R12 post-mortem) ----------------
__global__ __launch_bounds__(256) void k_agg(const u16* __restrict__ xlb,
        const float* __restrict__ a_s, const float* __restrict__ a_d,
        const int* __restrict__ row_ptr, const int* __restrict__ col_src,
        const float* __restrict__ bias, u16* __restrict__ gb_out) {
    int wave = threadIdx.x >> 6, lane = threadIdx.x & 63;
    int dst = blockIdx.x * 2 + (wave >> 1);
    int bp = (wave & 1) * 2;
    int beg = row_ptr[dst], end = row_ptr[dst + 1];

    // pass 1: exact max per (b,h); 8-way edge split across replica groups
    int c = lane & 7, g = lane >> 3;
    int bc = bp + (c >> 2), hc = c & 3;
    float adv1 = a_d[(size_t)dst * 16 + bc * 4 + hc];
    float mloc = -INFINITY;
    for (int i = beg + g; i < end; i += 8) {
        int src = min(max(col_src[i], 0), NNODE - 1);
        float e = a_s[(size_t)src * 16 + bc * 4 + hc] + adv1;
        e = (e >= 0.f) ? e : 0.2f * e;
        mloc = fmaxf(mloc, e);
    }
    mloc = fmaxf(mloc, __shfl_xor(mloc, 8, 64));
    mloc = fmaxf(mloc, __shfl_xor(mloc, 16, 64));
    mloc = fmaxf(mloc, __shfl_xor(mloc, 32, 64));

    int bl = lane >> 5;
    int s = lane & 31;
    int h = s >> 3;
    int b = bp + bl;
    float mv = __shfl(mloc, bl * 4 + h, 64);

    // pass 2: depth-1 prefetch, named scalars
    float advh = a_d[(size_t)dst * 16 + b * 4 + h];
    float acc[8];
    #pragma unroll
    for (int k = 0; k < 8; ++k) acc[k] = 0.f;
    float l = 0.f;

    int i = beg;
    float as_c = 0.f; short8 x_c = {0};
    if (i < end) {
        int src = min(max(col_src[i], 0), NNODE - 1);
        as_c = a_s[(size_t)src * 16 + b * 4 + h];
        x_c = *(const short8*)&xlb[((size_t)src * 4 + b) * 256 + s * 8];
    }
    while (i < end) {
        int inext = i + 1;
        float as_n = 0.f; short8 x_n = {0};
        if (inext < end) {
            int src = min(max(col_src[inext], 0), NNODE - 1);
            as_n = a_s[(size_t)src * 16 + b * 4 + h];
            x_n = *(const short8*)&xlb[((size_t)src * 4 + b) * 256 + s * 8];
        }
        float e = as_c + advh;
        e = (e >= 0.f) ? e : 0.2f * e;
        float p = __expf(e - mv);
        l += p;
        #pragma unroll
        for (int k = 0; k < 8; ++k) acc[k] += p * u2f((u16)x_c[k]);
        as_c = as_n; x_c = x_n;
        i = inext;
    }
    float rl = 1.f / (l + 1e-16f);
    short8 o;
    #pragma unroll
    for (int k = 0; k < 8; ++k)
        o[k] = (short)f2b(prelu(acc[k] * rl + bias[s * 8 + k]));
    *(short8*)&gb_out[((size_t)dst * 4 + b) * 256 + s * 8] = o;
}

// ---------------- attribution head (blocks <625) + pooled sum (blocks >=625) ----------
__global__ __launch_bounds__(256) void k_attrpool(const u16* __restrict__ gb,
        const u16* __restrict__ Wa1t, const float* __restrict__ wbuf,
        float* __restrict__ out, float* __restrict__ pooled) {
    if (blockIdx.x >= 625) {   // pool part
        int pb = blockIdx.x - 625;
        int b = pb >> 6;
        int chunk = pb & 63;
        int cch = threadIdx.x;
        int n0 = chunk * 157;
        int n1 = min(NNODE, n0 + 157);
        float acc = 0.f;
        for (int n = n0; n < n1; ++n)
            acc += u2f(gb[((size_t)n * 4 + b) * 256 + cch]);
        atomicAdd(&pooled[b * 256 + cch], acc);
        return;
    }
    int wave = threadIdx.x >> 6, lane = threadIdx.x & 63;
    int row0 = (blockIdx.x * 4 + wave) * 16;
    int m = lane & 15, q = lane >> 4;
    f32x4 acc[4];
    #pragma unroll
    for (int nt = 0; nt < 4; ++nt) acc[nt] = {0.f, 0.f, 0.f, 0.f};
    for (int kc = 0; kc < 256; kc += 32) {
        short8 a = *(const short8*)&gb[(size_t)(row0 + m) * 256 + kc + q * 8];
        #pragma unroll
        for (int nt = 0; nt < 4; ++nt) {
            short8 b = *(const short8*)&Wa1t[(size_t)(nt * 16 + m) * 256 + kc + q * 8];
            acc[nt] = __builtin_amdgcn_mfma_f32_16x16x32_bf16(a, b, acc[nt], 0, 0, 0);
        }
    }
    float part[4] = {0, 0, 0, 0};
    #pragma unroll
    for (int nt = 0; nt < 4; ++nt) {
        int col = nt * 16 + m;
        float ba1v = wbuf[S_BA1 + col];
        float wa2v = wbuf[S_WA2 + col];
        #pragma unroll
        for (int r = 0; r < 4; ++r)
            part[r] += prelu(acc[nt][r] + ba1v) * wa2v;
    }
    #pragma unroll
    for (int off = 1; off < 16; off <<= 1) {
        #pragma unroll
        for (int r = 0; r < 4; ++r)
            part[r] += __shfl_xor(part[r], off, 64);
    }
    if (m == 0) {
        float ba2v = wbuf[S_BA2];
        #pragma unroll
        for (int r = 0; r < 4; ++r) {
            int row = row0 + q * 4 + r;
            int n = row >> 2, b = row & 3;
            float v = part[r] + ba2v;
            out[8 + b * NNODE + n] = 1.f / (1.f + __expf(-v));
        }
    }
}

// ---------------- classification head (blocks 0-3) + diagnostics (block 4) ----------
__global__ __launch_bounds__(128) void k_logits(const float* __restrict__ pooled,
        const float* __restrict__ wbuf, const void* __restrict__ Wc1p,
        float* __restrict__ out,
        const u16* __restrict__ featb, const u16* __restrict__ gb,
        const int* __restrict__ row_ptr, const int* __restrict__ ei,
        const void* __restrict__ xsrc, int hostbad) {
    int tid = threadIdx.x;
    bool isbf = probe_x_bf16(xsrc);
    if (blockIdx.x == 4) {   // sampled diagnostics
        __shared__ float red[128];
        bool ei64 = probe_ei64(ei);
        float mx[2] = {0.f, 0.f};
        const u16* bufs[2] = {featb, gb};
        for (int qq = 0; qq < 2; ++qq) {
            const u16* p = bufs[qq];
            float m = 0.f;
            for (int i = tid; i < 2048; i += 128) {
                float v = u2f(p[i]);
                if (v != v) m = 1e30f;
                m = fmaxf(m, fabsf(v));
            }
            red[tid] = m;
            __syncthreads();
            for (int s2 = 64; s2 > 0; s2 >>= 1) {
                if (tid < s2) red[tid] = fmaxf(red[tid], red[tid + s2]);
                __syncthreads();
            }
            mx[qq] = red[0];
            __syncthreads();
        }
        if (tid == 0) {
            int fb = (mx[0] > 1e8f || mx[0] < 1e-6f) ? 1 : 0;
            int gbad = (mx[1] > 1e8f || mx[1] < 1e-6f) ? 1 : 0;
            int cb = (row_ptr[NNODE] != NEDGE + NNODE) ? 1 : 0;
            int code = 100 * fb + 400 * gbad + 800 * cb + 6400 * hostbad;
            if (code) {
                code += 1600 * (isbf ? 0 : 1);
                code += 3200 * (ei64 ? 1 : 0);
                for (int j = 0; j < 8; ++j) out[j] = (float)code;
            }
        }
        return;
    }
    __shared__ float pm[256];
    __shared__ float red4[4];
    int b = blockIdx.x;
    pm[tid] = pooled[b * 256 + tid] * (1.f / NNODE);
    pm[tid + 128] = pooled[b * 256 + tid + 128] * (1.f / NNODE);
    __syncthreads();
    float acc = wbuf[S_BC1 + tid];
    if (isbf) {
        const u16* w = (const u16*)Wc1p;
        #pragma unroll 4
        for (int k = 0; k < 256; ++k)
            acc += pm[k] * u2f(w[k * 128 + tid]);
    } else {
        const float* w = (const float*)Wc1p;
        #pragma unroll 4
        for (int k = 0; k < 256; ++k)
            acc += pm[k] * w[k * 128 + tid];
    }
    float hv = prelu(acc);
    float p0 = hv * wbuf[S_WC2 + tid * 2];
    float p1 = hv * wbuf[S_WC2 + tid * 2 + 1];
    #pragma unroll
    for (int off = 32; off > 0; off >>= 1) {
        p0 += __shfl_xor(p0, off, 64);
        p1 += __shfl_xor(p1, off, 64);
    }
    int wv = tid >> 6, lane = tid & 63;
    if (lane == 0) { red4[wv * 2] = p0; red4[wv * 2 + 1] = p1; }
    __syncthreads();
    if (tid < 2)
        out[b * 2 + tid] = red4[tid] + red4[2 + tid] + wbuf[S_BC2 + tid];
}

extern "C" void kernel_launch(void* const* d_in, const int* in_sizes, int n_in,
                              void* d_out, int out_size, void* d_ws, size_t ws_size,
                              hipStream_t stream) {
    const void* x  = d_in[0];
    const int*  ei = (const int*)d_in[1];
    float* out = (float*)d_out;

    WPtrs wp;
    for (int j = 0; j < 20; ++j) wp.p[j] = d_in[j + 2];

    char* ws = (char*)d_ws;
    size_t off = 0;
    auto alloc = [&](size_t bytes) -> void* {
        void* p = ws + off;
        off += (bytes + 255) & ~(size_t)255;
        return p;
    };
    float* wbuf    = (float*)alloc((size_t)S_TOTAL * 4);
    u16*   featb   = (u16*)  alloc((size_t)BATCH * NNODE * 64 * 2);
    u16*   xlb     = (u16*)  alloc((size_t)BATCH * NNODE * 256 * 2);
    u16*   gb      = (u16*)  alloc((size_t)BATCH * NNODE * 256 * 2);
    float* a_s     = (float*)alloc((size_t)BATCH * NNODE * 4 * 4);
    float* a_d     = (float*)alloc((size_t)BATCH * NNODE * 4 * 4);
    u16*   cw2r    = (u16*)alloc(6144 * 2);
    u16*   W0t     = (u16*)alloc(16384 * 2);
    u16*   W1t     = (u16*)alloc(65536 * 2);
    u16*   Wa1t    = (u16*)alloc(16384 * 2);
    // counts and pooled ADJACENT: one memset zeroes both
    int*   counts  = (int*)alloc(NNODE * 4);           // padded to 40192
    float* pooled  = (float*)alloc(BATCH * 256 * 4);   // 4096
    int*   row_ptr = (int*)alloc((NNODE + 1) * 4);
    int*   cur     = (int*)alloc(NNODE * 4);
    int*   col_src = (int*)alloc((NEDGE + NNODE) * 4);
    int*   bsum    = (int*)alloc(64 * 4);
    (void)ws_size; (void)out_size;

    int hostbad = (n_in != 22 || in_sizes[0] != BATCH * NNODE * TLEN ||
                   in_sizes[1] != 2 * NEDGE) ? 1 : 0;

    int eg = (NEDGE + NNODE + 255) / 256;

    hipMemsetAsync(counts, 0, 40192 + 4096, stream);

    k_pre<<<PRE_TBLK + 9, 256, 0, stream>>>(wp, x, ei, wbuf, cw2r, W0t, W1t, Wa1t, counts);
    k_scan1<<<40, 256, 0, stream>>>(counts, cur, bsum);
    k_scan3<<<40, 256, 0, stream>>>(counts, cur, bsum, row_ptr);
    k_fill<<<eg, 256, 0, stream>>>(ei, cur, col_src);

    k_conv<<<BATCH * NNODE / 4, 256, 0, stream>>>(x, wbuf, cw2r, featb);

    // GAT layer 0
    k_gemm<64><<<BATCH * NNODE / 64, 256, 0, stream>>>(featb, W0t,
            wbuf + S_AS0, wbuf + S_AD0, xlb, a_s, a_d);
    k_agg<<<NNODE / 2, 256, 0, stream>>>(xlb, a_s, a_d, row_ptr, col_src, wbuf + S_B0, gb);

    // GAT layer 1
    k_gemm<256><<<BATCH * NNODE / 64, 256, 0, stream>>>(gb, W1t,
            wbuf + S_AS1, wbuf + S_AD1, xlb, a_s, a_d);
    k_agg<<<NNODE / 2, 256, 0, stream>>>(xlb, a_s, a_d, row_ptr, col_src, wbuf + S_B1, gb);

    // heads
    k_attrpool<<<625 + 256, 256, 0, stream>>>(gb, Wa1t, wbuf, out, pooled);
    k_logits<<<5, 128, 0, stream>>>(pooled, wbuf, wp.p[12], out, featb, gb, row_ptr, ei, x, hostbad);
}

// Round 14
// 418.254 us; speedup vs baseline: 3.9622x; 1.1314x over previous
//
#include <hip/hip_runtime.h>
#include <hip/hip_bf16.h>
#include <math.h>

typedef __hip_bfloat16 bf16;
typedef unsigned short u16;
typedef unsigned int u32;
typedef __attribute__((ext_vector_type(8))) short short8;
typedef __attribute__((ext_vector_type(4))) float f32x4;
typedef __attribute__((ext_vector_type(2))) float f32x2;

#define BATCH 4
#define NNODE 10000
#define TLEN 128
#define NEDGE 160000
#define GDIM 256
#define NHEAD 4

// small-weight fp32 staging offsets (everything except W0/W1/Wa1/Wc1)
#define S_CW1 0
#define S_CB1 96
#define S_CB2 128
#define S_AS0 192
#define S_AD0 448
#define S_B0  704
#define S_AS1 960
#define S_AD1 1216
#define S_B1  1472
#define S_BC1 1728
#define S_WC2 1856
#define S_BC2 2112
#define S_BA1 2114
#define S_WA2 2178
#define S_BA2 2242
#define S_TOTAL 2243

__device__ __forceinline__ float prelu(float v) { return 0.5f * (v + fabsf(v)); }
__device__ __forceinline__ u16 f2b(float f) {
    union { float f; u32 u; } v; v.f = f;
    u32 r = v.u + 0x7FFF + ((v.u >> 16) & 1);
    return (u16)(r >> 16);
}
__device__ __forceinline__ float u2f(u16 u) {
    union { u32 u; float f; } v; v.u = ((u32)u) << 16;
    return v.f;
}
__device__ __forceinline__ float ldw(const void* p, int off, bool isbf) {
    return isbf ? u2f(((const u16*)p)[off]) : ((const float*)p)[off];
}

// per-wave inline dtype probes (all waves compute identical results)
__device__ __forceinline__ bool probe_x_bf16(const void* xsrc) {
    int lane = threadIdx.x & 63;
    u16 h = ((const u16*)xsrc)[2 * lane];
    int e = (h >> 7) & 0xFF;
    unsigned long long m = __ballot(e >= 117 && e <= 130);
    return __popcll(m) >= 32;
}
__device__ __forceinline__ bool probe_ei64(const int* ei) {
    int lane = threadIdx.x & 63;
    int v = ei[2 * lane + 1];
    unsigned long long m = __ballot(v == 0);
    return __popcll(m) >= 56;
}

struct WPtrs { const void* p[20]; };

// ------ merged: bf16 transposes + dst histogram + small-weight fp32 staging ------
#define PRE_TBLK 665   // covers max(65536, 170000) indices
__global__ __launch_bounds__(256) void k_pre(WPtrs wp, const void* __restrict__ xsrc,
        const int* __restrict__ ei, float* __restrict__ wbuf,
        u16* __restrict__ cw2r, u16* __restrict__ W0t, u16* __restrict__ W1t,
        u16* __restrict__ Wa1t, int* __restrict__ counts) {
    bool isbf = probe_x_bf16(xsrc);
    int b = blockIdx.x;
    if (b >= PRE_TBLK) {   // small-weight staging (9 blocks)
        const int C2[16] = {0,96,128,192,448,704,960,1216,1472,1728,1856,2112,
                            2114,2178,2242,2243};
        const int SRC[15] = {0,1,3,5,6,7,9,10,11,13,14,15,17,18,19};
        int i = (b - PRE_TBLK) * 256 + threadIdx.x;
        if (i >= S_TOTAL) return;
        int j = 14;
        for (int t = 0; t < 15; ++t) { if (i < C2[t + 1]) { j = t; break; } }
        wbuf[i] = ldw(wp.p[SRC[j]], i - C2[j], isbf);
        return;
    }
    int i = b * 256 + threadIdx.x;
    if (i < 6144) {   // cw2r[c2][k'=dk*32+ci]
        int c2 = i / 96, k = i - c2 * 96, s = k >> 5, ci = k & 31;
        cw2r[i] = f2b(ldw(wp.p[2], c2 * 96 + ci * 3 + s, isbf));
    }
    if (i < 16384) {  // W0t / Wa1t, coalesced reads
        int k = i >> 8, c = i & 255;
        W0t[c * 64 + k] = f2b(ldw(wp.p[4], k * 256 + c, isbf));
        int ka = i >> 6, ca = i & 63;
        Wa1t[ca * 256 + ka] = f2b(ldw(wp.p[16], ka * 64 + ca, isbf));
    }
    if (i < 65536) {  // W1t
        int k = i >> 8, c = i & 255;
        W1t[c * 256 + k] = f2b(ldw(wp.p[8], k * 256 + c, isbf));
    }
    if (i < NEDGE + NNODE) {   // dst histogram (counts pre-zeroed by memset)
        bool ei64 = probe_ei64(ei);
        int dst;
        if (i < NEDGE) dst = ei64 ? ei[2 * (NEDGE + i)] : ei[NEDGE + i];
        else dst = i - NEDGE;
        if (dst >= 0 && dst < NNODE) atomicAdd(&counts[dst], 1);
    }
}

// ---------------- parallel scan ----------------
__global__ __launch_bounds__(256) void k_scan1(const int* __restrict__ counts,
        int* __restrict__ cur, int* __restrict__ bsum) {
    __shared__ int buf[256];
    int tid = threadIdx.x;
    int i = blockIdx.x * 256 + tid;
    int v = (i < NNODE) ? counts[i] : 0;
    buf[tid] = v;
    __syncthreads();
    for (int off = 1; off < 256; off <<= 1) {
        int t = (tid >= off) ? buf[tid - off] : 0;
        __syncthreads();
        buf[tid] += t;
        __syncthreads();
    }
    if (i < NNODE) cur[i] = buf[tid];
    if (tid == 255) bsum[blockIdx.x] = buf[255];
}
__global__ __launch_bounds__(256) void k_scan3(const int* __restrict__ counts,
        int* __restrict__ cur, const int* __restrict__ bsum, int* __restrict__ row_ptr) {
    __shared__ int pre_s;
    int tid = threadIdx.x;
    if (tid == 0) {
        int s = 0;
        for (int j = 0; j < blockIdx.x; ++j) s += bsum[j];
        pre_s = s;
    }
    __syncthreads();
    int i = blockIdx.x * 256 + tid;
    if (i >= NNODE) return;
    int incl = cur[i] + pre_s;
    row_ptr[i + 1] = incl;
    cur[i] = incl - counts[i];
    if (i == 0) row_ptr[0] = 0;
}

// ---------------- fused temporal conv + CSR fill (blocks < 665 do a fill slice) -------
#define HSTR 40
#define WSTR 96
#define FILL_BLK 665
__global__ __launch_bounds__(256) void k_conv(const void* __restrict__ xsrc,
        const float* __restrict__ wbuf, const u16* __restrict__ cw2r,
        u16* __restrict__ featb, const int* __restrict__ ei,
        int* __restrict__ cur, int* __restrict__ col_src) {
    __shared__ __align__(16) float xs[4][132];
    __shared__ float w1s[96], b1s[32], b2s[64];
    __shared__ __align__(16) u16 w2s[64 * WSTR];
    __shared__ __align__(16) u16 hs[66 * HSTR];
    __shared__ float red2[4][64];

    bool isbf = probe_x_bf16(xsrc);
    int tid = threadIdx.x;
    int wave = tid >> 6, lane = tid & 63;
    int node0 = blockIdx.x * 4;

    {
        int j = tid >> 6, p = (tid & 63) * 2;
        if (isbf) {
            u32 w = ((const u32*)xsrc)[(size_t)node0 * 64 + tid];
            xs[j][1 + p] = u2f((u16)(w & 0xFFFF));
            xs[j][2 + p] = u2f((u16)(w >> 16));
        } else {
            float2 w = ((const float2*)xsrc)[(size_t)node0 * 64 + tid];
            xs[j][1 + p] = w.x;
            xs[j][2 + p] = w.y;
        }
    }
    if (tid < 8) xs[tid >> 1][(tid & 1) ? 129 : 0] = 0.f;
    if (tid < 96) w1s[tid] = wbuf[S_CW1 + tid];
    if (tid < 32) b1s[tid] = wbuf[S_CB1 + tid];
    if (tid < 64) b2s[tid] = wbuf[S_CB2 + tid];
    for (int i = tid; i < 768; i += 256)
        ((short8*)w2s)[i] = ((const short8*)cw2r)[i];   // identity: WSTR == 96
    if (tid < 32) hs[tid] = 0;
    else if (tid < 64) hs[65 * HSTR + (tid - 32)] = 0;
    __syncthreads();

    int d = tid & 15, uu = tid >> 4;
    float wa0 = w1s[6 * d + 0], wa1 = w1s[6 * d + 1], wa2 = w1s[6 * d + 2];
    float wb0 = w1s[6 * d + 3], wb1 = w1s[6 * d + 4], wb2 = w1s[6 * d + 5];
    float ba = b1s[2 * d], bb = b1s[2 * d + 1];
    int m = lane & 15, q = lane >> 4;
    int trow = wave * 16 + m;

    for (int j = 0; j < 4; ++j) {
        const float* xr = &xs[j][0];
        #pragma unroll
        for (int it = 0; it < 4; ++it) {
            int u = uu + 16 * it;
            int t0 = 2 * u;
            float x0 = xr[t0], x1 = xr[t0 + 1], x2 = xr[t0 + 2], x3 = xr[t0 + 3];
            f32x2 A = {x0, x1}, Bv = {x1, x2}, Cv = {x2, x3};
            f32x2 va = {ba, ba}; va += wa0 * A; va += wa1 * Bv; va += wa2 * Cv;
            f32x2 vb = {bb, bb}; vb += wb0 * A; vb += wb1 * Bv; vb += wb2 * Cv;
            float ha = fmaxf(fmaxf(va.x, va.y), 0.f);
            float hb = fmaxf(fmaxf(vb.x, vb.y), 0.f);
            __hip_bfloat162 hp2 = __float22bfloat162_rn(make_float2(ha, hb));
            u32 pack; __builtin_memcpy(&pack, &hp2, 4);
            *(u32*)&hs[(u + 1) * HSTR + 2 * d] = pack;
        }
        __syncthreads();

        short8 afr[3];
        #pragma unroll
        for (int s = 0; s < 3; ++s)
            afr[s] = *(const short8*)&hs[(trow + s) * HSTR + q * 8];
        float psum[4];
        #pragma unroll
        for (int nt = 0; nt < 4; ++nt) {
            int n = nt * 16 + m;
            f32x4 acc = {0.f, 0.f, 0.f, 0.f};
            #pragma unroll
            for (int s = 0; s < 3; ++s) {
                short8 bfr = *(const short8*)&w2s[n * WSTR + s * 32 + q * 8];
                acc = __builtin_amdgcn_mfma_f32_16x16x32_bf16(afr[s], bfr, acc, 0, 0, 0);
            }
            float b2v = b2s[n];
            float scl = prelu(acc[0] + b2v) + prelu(acc[1] + b2v)
                      + prelu(acc[2] + b2v) + prelu(acc[3] + b2v);
            scl += __shfl_xor(scl, 16, 64);
            scl += __shfl_xor(scl, 32, 64);
            psum[nt] = scl;
        }
        if (lane < 16) {
            #pragma unroll
            for (int nt = 0; nt < 4; ++nt)
                red2[wave][nt * 16 + lane] = psum[nt];
        }
        __syncthreads();
        if (tid < 64) {
            float tot = (red2[0][tid] + red2[1][tid] + red2[2][tid] + red2[3][tid]) * (1.f / 64.f);
            int node = node0 + j;
            int bb2 = node / NNODE, nn = node - bb2 * NNODE;
            featb[((size_t)nn * 4 + bb2) * 64 + tid] = f2b(tot);
        }
    }

    // ---- CSR fill slice (blocks < FILL_BLK); cur ready since k_conv follows k_scan3;
    // col_src consumed only by k_agg, launched later ----
    if (blockIdx.x < FILL_BLK) {
        bool ei64 = probe_ei64(ei);
        int e = blockIdx.x * 256 + tid;
        if (e < NEDGE + NNODE) {
            int src, dst;
            if (e < NEDGE) {
                if (ei64) { src = ei[2 * e]; dst = ei[2 * (NEDGE + e)]; }
                else      { src = ei[e];     dst = ei[NEDGE + e]; }
            } else {
                src = dst = e - NEDGE;
            }
            if (dst >= 0 && dst < NNODE) {
                int pos = atomicAdd(&cur[dst], 1);
                if (pos >= 0 && pos < NEDGE + NNODE) col_src[pos] = src;
            }
        }
    }
}

// ------ zero-LDS MFMA GEMM (MT=1), fused attention scores ------
template<int K>
__global__ __launch_bounds__(256) void k_gemm(const u16* __restrict__ A,
        const u16* __restrict__ Wt, const float* __restrict__ att_s_w,
        const float* __restrict__ att_d_w, u16* __restrict__ outb,
        float* __restrict__ a_s, float* __restrict__ a_d) {
    int wave = threadIdx.x >> 6, lane = threadIdx.x & 63;
    int row0 = (blockIdx.x * 4 + wave) * 16;
    int m = lane & 15, q = lane >> 4;
    f32x4 acc[16];
    #pragma unroll
    for (int nt = 0; nt < 16; ++nt) acc[nt] = {0.f, 0.f, 0.f, 0.f};
    for (int kc = 0; kc < K; kc += 32) {
        short8 a = *(const short8*)&A[(size_t)(row0 + m) * K + kc + q * 8];
        #pragma unroll
        for (int nt = 0; nt < 16; ++nt) {
            short8 b = *(const short8*)&Wt[(size_t)(nt * 16 + m) * K + kc + q * 8];
            acc[nt] = __builtin_amdgcn_mfma_f32_16x16x32_bf16(a, b, acc[nt], 0, 0, 0);
        }
    }
    #pragma unroll
    for (int nt = 0; nt < 16; ++nt) {
        #pragma unroll
        for (int r = 0; r < 4; ++r)
            outb[(size_t)(row0 + q * 4 + r) * 256 + nt * 16 + m] = f2b(acc[nt][r]);
    }
    float sh_s[4][4] = {{0}}, sh_d[4][4] = {{0}};
    #pragma unroll
    for (int nt = 0; nt < 16; ++nt) {
        int h = nt >> 2;
        int cc = (nt & 3) * 16 + m;
        float asw = att_s_w[h * 64 + cc];
        float adw = att_d_w[h * 64 + cc];
        #pragma unroll
        for (int r = 0; r < 4; ++r) {
            sh_s[h][r] += acc[nt][r] * asw;
            sh_d[h][r] += acc[nt][r] * adw;
        }
    }
    #pragma unroll
    for (int off = 1; off < 16; off <<= 1) {
        #pragma unroll
        for (int h = 0; h < 4; ++h)
            #pragma unroll
            for (int r = 0; r < 4; ++r) {
                sh_s[h][r] += __shfl_xor(sh_s[h][r], off, 64);
                sh_d[h][r] += __shfl_xor(sh_d[h][r], off, 64);
            }
    }
    if (m == 0) {
        #pragma unroll
        for (int r = 0; r < 4; ++r) {
            int row = row0 + q * 4 + r;
            float4 vs = {sh_s[0][r], sh_s[1][r], sh_s[2][r], sh_s[3][r]};
            float4 vd = {sh_d[0][r], sh_d[1][r], sh_d[2][r], sh_d[3][r]};
            *(float4*)&a_s[(size_t)row * 4] = vs;
            *(float4*)&a_d[(size_t)row * 4] = vd;
        }
    }
}

// ---------------- GAT aggregation: pass-2 chunk-4 MLP unroll, NAMED scalars only ------
__global__ __launch_bounds__(256) void k_agg(const u16* __restrict__ xlb,
        const float* __restrict__ a_s, const float* __restrict__ a_d,
        const int* __restrict__ row_ptr, const int* __restrict__ col_src,
        const float* __restrict__ bias, u16* __restrict__ gb_out) {
    int wave = threadIdx.x >> 6, lane = threadIdx.x & 63;
    int dst = blockIdx.x * 2 + (wave >> 1);
    int bp = (wave & 1) * 2;
    int beg = row_ptr[dst], end = row_ptr[dst + 1];

    // pass 1: exact max per (b,h); 8-way edge split across replica groups
    int c = lane & 7, g = lane >> 3;
    int bc = bp + (c >> 2), hc = c & 3;
    float adv1 = a_d[(size_t)dst * 16 + bc * 4 + hc];
    float mloc = -INFINITY;
    for (int i = beg + g; i < end; i += 8) {
        int src = min(max(col_src[i], 0), NNODE - 1);
        float e = a_s[(size_t)src * 16 + bc * 4 + hc] + adv1;
        e = (e >= 0.f) ? e : 0.2f * e;
        mloc = fmaxf(mloc, e);
    }
    mloc = fmaxf(mloc, __shfl_xor(mloc, 8, 64));
    mloc = fmaxf(mloc, __shfl_xor(mloc, 16, 64));
    mloc = fmaxf(mloc, __shfl_xor(mloc, 32, 64));

    int bl = lane >> 5;
    int s = lane & 31;
    int h = s >> 3;
    int b = bp + bl;
    float mv = __shfl(mloc, bl * 4 + h, 64);

    // pass 2: chunk-4 unroll — 4 col_src (contiguous) + 4 a_s + 4 xlb loads in flight.
    // Accumulation order preserved (s0->s3 sequential) => bit-identical to scalar loop.
    float advh = a_d[(size_t)dst * 16 + b * 4 + h];
    float acc[8];
    #pragma unroll
    for (int k = 0; k < 8; ++k) acc[k] = 0.f;
    float l = 0.f;

    int asoff = b * 4 + h;
    int i = beg;
    for (; i + 4 <= end; i += 4) {
        int s0 = min(max(col_src[i], 0), NNODE - 1);
        int s1 = min(max(col_src[i + 1], 0), NNODE - 1);
        int s2 = min(max(col_src[i + 2], 0), NNODE - 1);
        int s3 = min(max(col_src[i + 3], 0), NNODE - 1);
        float a0 = a_s[(size_t)s0 * 16 + asoff];
        float a1 = a_s[(size_t)s1 * 16 + asoff];
        float a2 = a_s[(size_t)s2 * 16 + asoff];
        float a3 = a_s[(size_t)s3 * 16 + asoff];
        short8 x0 = *(const short8*)&xlb[((size_t)s0 * 4 + b) * 256 + s * 8];
        short8 x1 = *(const short8*)&xlb[((size_t)s1 * 4 + b) * 256 + s * 8];
        short8 x2 = *(const short8*)&xlb[((size_t)s2 * 4 + b) * 256 + s * 8];
        short8 x3 = *(const short8*)&xlb[((size_t)s3 * 4 + b) * 256 + s * 8];
        float e0 = a0 + advh; e0 = (e0 >= 0.f) ? e0 : 0.2f * e0;
        float p0 = __expf(e0 - mv); l += p0;
        #pragma unroll
        for (int k = 0; k < 8; ++k) acc[k] += p0 * u2f((u16)x0[k]);
        float e1 = a1 + advh; e1 = (e1 >= 0.f) ? e1 : 0.2f * e1;
        float p1 = __expf(e1 - mv); l += p1;
        #pragma unroll
        for (int k = 0; k < 8; ++k) acc[k] += p1 * u2f((u16)x1[k]);
        float e2 = a2 + advh; e2 = (e2 >= 0.f) ? e2 : 0.2f * e2;
        float p2 = __expf(e2 - mv); l += p2;
        #pragma unroll
        for (int k = 0; k < 8; ++k) acc[k] += p2 * u2f((u16)x2[k]);
        float e3 = a3 + advh; e3 = (e3 >= 0.f) ? e3 : 0.2f * e3;
        float p3 = __expf(e3 - mv); l += p3;
        #pragma unroll
        for (int k = 0; k < 8; ++k) acc[k] += p3 * u2f((u16)x3[k]);
    }
    for (; i < end; ++i) {
        int s0 = min(max(col_src[i], 0), NNODE - 1);
        float a0 = a_s[(size_t)s0 * 16 + asoff];
        short8 x0 = *(const short8*)&xlb[((size_t)s0 * 4 + b) * 256 + s * 8];
        float e0 = a0 + advh; e0 = (e0 >= 0.f) ? e0 : 0.2f * e0;
        float p0 = __expf(e0 - mv); l += p0;
        #pragma unroll
        for (int k = 0; k < 8; ++k) acc[k] += p0 * u2f((u16)x0[k]);
    }
    float rl = 1.f / (l + 1e-16f);
    short8 o;
    #pragma unroll
    for (int k = 0; k < 8; ++k)
        o[k] = (short)f2b(prelu(acc[k] * rl + bias[s * 8 + k]));
    *(short8*)&gb_out[((size_t)dst * 4 + b) * 256 + s * 8] = o;
}

// ---------------- attribution head (blocks <625) + pooled sum (blocks >=625) ----------
__global__ __launch_bounds__(256) void k_attrpool(const u16* __restrict__ gb,
        const u16* __restrict__ Wa1t, const float* __restrict__ wbuf,
        float* __restrict__ out, float* __restrict__ pooled) {
    if (blockIdx.x >= 625) {   // pool part, n-loop unrolled x4 (independent loads)
        int pb = blockIdx.x - 625;
        int b = pb >> 6;
        int chunk = pb & 63;
        int cch = threadIdx.x;
        int n0 = chunk * 157;
        int n1 = min(NNODE, n0 + 157);
        float acc = 0.f;
        int n = n0;
        for (; n + 4 <= n1; n += 4) {
            float v0 = u2f(gb[((size_t)n * 4 + b) * 256 + cch]);
            float v1 = u2f(gb[((size_t)(n + 1) * 4 + b) * 256 + cch]);
            float v2 = u2f(gb[((size_t)(n + 2) * 4 + b) * 256 + cch]);
            float v3 = u2f(gb[((size_t)(n + 3) * 4 + b) * 256 + cch]);
            acc += v0; acc += v1; acc += v2; acc += v3;
        }
        for (; n < n1; ++n)
            acc += u2f(gb[((size_t)n * 4 + b) * 256 + cch]);
        atomicAdd(&pooled[b * 256 + cch], acc);
        return;
    }
    int wave = threadIdx.x >> 6, lane = threadIdx.x & 63;
    int row0 = (blockIdx.x * 4 + wave) * 16;
    int m = lane & 15, q = lane >> 4;
    f32x4 acc[4];
    #pragma unroll
    for (int nt = 0; nt < 4; ++nt) acc[nt] = {0.f, 0.f, 0.f, 0.f};
    for (int kc = 0; kc < 256; kc += 32) {
        short8 a = *(const short8*)&gb[(size_t)(row0 + m) * 256 + kc + q * 8];
        #pragma unroll
        for (int nt = 0; nt < 4; ++nt) {
            short8 b = *(const short8*)&Wa1t[(size_t)(nt * 16 + m) * 256 + kc + q * 8];
            acc[nt] = __builtin_amdgcn_mfma_f32_16x16x32_bf16(a, b, acc[nt], 0, 0, 0);
        }
    }
    float part[4] = {0, 0, 0, 0};
    #pragma unroll
    for (int nt = 0; nt < 4; ++nt) {
        int col = nt * 16 + m;
        float ba1v = wbuf[S_BA1 + col];
        float wa2v = wbuf[S_WA2 + col];
        #pragma unroll
        for (int r = 0; r < 4; ++r)
            part[r] += prelu(acc[nt][r] + ba1v) * wa2v;
    }
    #pragma unroll
    for (int off = 1; off < 16; off <<= 1) {
        #pragma unroll
        for (int r = 0; r < 4; ++r)
            part[r] += __shfl_xor(part[r], off, 64);
    }
    if (m == 0) {
        float ba2v = wbuf[S_BA2];
        #pragma unroll
        for (int r = 0; r < 4; ++r) {
            int row = row0 + q * 4 + r;
            int n = row >> 2, b = row & 3;
            float v = part[r] + ba2v;
            out[8 + b * NNODE + n] = 1.f / (1.f + __expf(-v));
        }
    }
}

// ---------------- classification head (blocks 0-3) + diagnostics (block 4) ----------
__global__ __launch_bounds__(128) void k_logits(const float* __restrict__ pooled,
        const float* __restrict__ wbuf, const void* __restrict__ Wc1p,
        float* __restrict__ out,
        const u16* __restrict__ featb, const u16* __restrict__ gb,
        const int* __restrict__ row_ptr, const int* __restrict__ ei,
        const void* __restrict__ xsrc, int hostbad) {
    int tid = threadIdx.x;
    bool isbf = probe_x_bf16(xsrc);
    if (blockIdx.x == 4) {   // sampled diagnostics
        __shared__ float red[128];
        bool ei64 = probe_ei64(ei);
        float mx[2] = {0.f, 0.f};
        const u16* bufs[2] = {featb, gb};
        for (int qq = 0; qq < 2; ++qq) {
            const u16* p = bufs[qq];
            float m = 0.f;
            for (int i = tid; i < 2048; i += 128) {
                float v = u2f(p[i]);
                if (v != v) m = 1e30f;
                m = fmaxf(m, fabsf(v));
            }
            red[tid] = m;
            __syncthreads();
            for (int s2 = 64; s2 > 0; s2 >>= 1) {
                if (tid < s2) red[tid] = fmaxf(red[tid], red[tid + s2]);
                __syncthreads();
            }
            mx[qq] = red[0];
            __syncthreads();
        }
        if (tid == 0) {
            int fb = (mx[0] > 1e8f || mx[0] < 1e-6f) ? 1 : 0;
            int gbad = (mx[1] > 1e8f || mx[1] < 1e-6f) ? 1 : 0;
            int cb = (row_ptr[NNODE] != NEDGE + NNODE) ? 1 : 0;
            int code = 100 * fb + 400 * gbad + 800 * cb + 6400 * hostbad;
            if (code) {
                code += 1600 * (isbf ? 0 : 1);
                code += 3200 * (ei64 ? 1 : 0);
                for (int j = 0; j < 8; ++j) out[j] = (float)code;
            }
        }
        return;
    }
    __shared__ float pm[256];
    __shared__ float red4[4];
    int b = blockIdx.x;
    pm[tid] = pooled[b * 256 + tid] * (1.f / NNODE);
    pm[tid + 128] = pooled[b * 256 + tid + 128] * (1.f / NNODE);
    __syncthreads();
    float acc = wbuf[S_BC1 + tid];
    if (isbf) {
        const u16* w = (const u16*)Wc1p;
        #pragma unroll 4
        for (int k = 0; k < 256; ++k)
            acc += pm[k] * u2f(w[k * 128 + tid]);
    } else {
        const float* w = (const float*)Wc1p;
        #pragma unroll 4
        for (int k = 0; k < 256; ++k)
            acc += pm[k] * w[k * 128 + tid];
    }
    float hv = prelu(acc);
    float p0 = hv * wbuf[S_WC2 + tid * 2];
    float p1 = hv * wbuf[S_WC2 + tid * 2 + 1];
    #pragma unroll
    for (int off = 32; off > 0; off >>= 1) {
        p0 += __shfl_xor(p0, off, 64);
        p1 += __shfl_xor(p1, off, 64);
    }
    int wv = tid >> 6, lane = tid & 63;
    if (lane == 0) { red4[wv * 2] = p0; red4[wv * 2 + 1] = p1; }
    __syncthreads();
    if (tid < 2)
        out[b * 2 + tid] = red4[tid] + red4[2 + tid] + wbuf[S_BC2 + tid];
}

extern "C" void kernel_launch(void* const* d_in, const int* in_sizes, int n_in,
                              void* d_out, int out_size, void* d_ws, size_t ws_size,
                              hipStream_t stream) {
    const void* x  = d_in[0];
    const int*  ei = (const int*)d_in[1];
    float* out = (float*)d_out;

    WPtrs wp;
    for (int j = 0; j < 20; ++j) wp.p[j] = d_in[j + 2];

    char* ws = (char*)d_ws;
    size_t off = 0;
    auto alloc = [&](size_t bytes) -> void* {
        void* p = ws + off;
        off += (bytes + 255) & ~(size_t)255;
        return p;
    };
    float* wbuf    = (float*)alloc((size_t)S_TOTAL * 4);
    u16*   featb   = (u16*)  alloc((size_t)BATCH * NNODE * 64 * 2);
    u16*   xlb     = (u16*)  alloc((size_t)BATCH * NNODE * 256 * 2);
    u16*   gb      = (u16*)  alloc((size_t)BATCH * NNODE * 256 * 2);
    float* a_s     = (float*)alloc((size_t)BATCH * NNODE * 4 * 4);
    float* a_d     = (float*)alloc((size_t)BATCH * NNODE * 4 * 4);
    u16*   cw2r    = (u16*)alloc(6144 * 2);
    u16*   W0t     = (u16*)alloc(16384 * 2);
    u16*   W1t     = (u16*)alloc(65536 * 2);
    u16*   Wa1t    = (u16*)alloc(16384 * 2);
    // counts and pooled ADJACENT: one memset zeroes both
    int*   counts  = (int*)alloc(NNODE * 4);           // padded to 40192
    float* pooled  = (float*)alloc(BATCH * 256 * 4);   // 4096
    int*   row_ptr = (int*)alloc((NNODE + 1) * 4);
    int*   cur     = (int*)alloc(NNODE * 4);
    int*   col_src = (int*)alloc((NEDGE + NNODE) * 4);
    int*   bsum    = (int*)alloc(64 * 4);
    (void)ws_size; (void)out_size;

    int hostbad = (n_in != 22 || in_sizes[0] != BATCH * NNODE * TLEN ||
                   in_sizes[1] != 2 * NEDGE) ? 1 : 0;

    hipMemsetAsync(counts, 0, 40192 + 4096, stream);

    k_pre<<<PRE_TBLK + 9, 256, 0, stream>>>(wp, x, ei, wbuf, cw2r, W0t, W1t, Wa1t, counts);
    k_scan1<<<40, 256, 0, stream>>>(counts, cur, bsum);
    k_scan3<<<40, 256, 0, stream>>>(counts, cur, bsum, row_ptr);

    // conv + CSR fill fused
    k_conv<<<BATCH * NNODE / 4, 256, 0, stream>>>(x, wbuf, cw2r, featb, ei, cur, col_src);

    // GAT layer 0
    k_gemm<64><<<BATCH * NNODE / 64, 256, 0, stream>>>(featb, W0t,
            wbuf + S_AS0, wbuf + S_AD0, xlb, a_s, a_d);
    k_agg<<<NNODE / 2, 256, 0, stream>>>(xlb, a_s, a_d, row_ptr, col_src, wbuf + S_B0, gb);

    // GAT layer 1
    k_gemm<256><<<BATCH * NNODE / 64, 256, 0, stream>>>(gb, W1t,
            wbuf + S_AS1, wbuf + S_AD1, xlb, a_s, a_d);
    k_agg<<<NNODE / 2, 256, 0, stream>>>(xlb, a_s, a_d, row_ptr, col_src, wbuf + S_B1, gb);

    // heads
    k_attrpool<<<625 + 256, 256, 0, stream>>>(gb, Wa1t, wbuf, out, pooled);
    k_logits<<<5, 128, 0, stream>>>(pooled, wbuf, wp.p[12], out, featb, gb, row_ptr, ei, x, hostbad);
}

// Round 15
// 414.407 us; speedup vs baseline: 3.9990x; 1.0093x over previous
//
#include <hip/hip_runtime.h>
#include <hip/hip_bf16.h>
#include <math.h>

typedef __hip_bfloat16 bf16;
typedef unsigned short u16;
typedef unsigned int u32;
typedef __attribute__((ext_vector_type(8))) short short8;
typedef __attribute__((ext_vector_type(4))) float f32x4;
typedef __attribute__((ext_vector_type(2))) float f32x2;

#define BATCH 4
#define NNODE 10000
#define TLEN 128
#define NEDGE 160000
#define GDIM 256
#define NHEAD 4

// small-weight fp32 staging offsets (everything except W0/W1/Wa1/Wc1)
#define S_CW1 0
#define S_CB1 96
#define S_CB2 128
#define S_AS0 192
#define S_AD0 448
#define S_B0  704
#define S_AS1 960
#define S_AD1 1216
#define S_B1  1472
#define S_BC1 1728
#define S_WC2 1856
#define S_BC2 2112
#define S_BA1 2114
#define S_WA2 2178
#define S_BA2 2242
#define S_TOTAL 2243

__device__ __forceinline__ float prelu(float v) { return 0.5f * (v + fabsf(v)); }
__device__ __forceinline__ u16 f2b(float f) {
    union { float f; u32 u; } v; v.f = f;
    u32 r = v.u + 0x7FFF + ((v.u >> 16) & 1);
    return (u16)(r >> 16);
}
__device__ __forceinline__ float u2f(u16 u) {
    union { u32 u; float f; } v; v.u = ((u32)u) << 16;
    return v.f;
}
__device__ __forceinline__ float ldw(const void* p, int off, bool isbf) {
    return isbf ? u2f(((const u16*)p)[off]) : ((const float*)p)[off];
}

// per-wave inline dtype probes (all waves compute identical results)
__device__ __forceinline__ bool probe_x_bf16(const void* xsrc) {
    int lane = threadIdx.x & 63;
    u16 h = ((const u16*)xsrc)[2 * lane];
    int e = (h >> 7) & 0xFF;
    unsigned long long m = __ballot(e >= 117 && e <= 130);
    return __popcll(m) >= 32;
}
__device__ __forceinline__ bool probe_ei64(const int* ei) {
    int lane = threadIdx.x & 63;
    int v = ei[2 * lane + 1];
    unsigned long long m = __ballot(v == 0);
    return __popcll(m) >= 56;
}

struct WPtrs { const void* p[20]; };

// ------ merged: bf16 transposes + dst histogram + small-weight fp32 staging ------
#define PRE_TBLK 665   // covers max(65536, 170000) indices
__global__ __launch_bounds__(256) void k_pre(WPtrs wp, const void* __restrict__ xsrc,
        const int* __restrict__ ei, float* __restrict__ wbuf,
        u16* __restrict__ cw2r, u16* __restrict__ W0t, u16* __restrict__ W1t,
        u16* __restrict__ Wa1t, int* __restrict__ counts) {
    bool isbf = probe_x_bf16(xsrc);
    int b = blockIdx.x;
    if (b >= PRE_TBLK) {   // small-weight staging (9 blocks)
        const int C2[16] = {0,96,128,192,448,704,960,1216,1472,1728,1856,2112,
                            2114,2178,2242,2243};
        const int SRC[15] = {0,1,3,5,6,7,9,10,11,13,14,15,17,18,19};
        int i = (b - PRE_TBLK) * 256 + threadIdx.x;
        if (i >= S_TOTAL) return;
        int j = 14;
        for (int t = 0; t < 15; ++t) { if (i < C2[t + 1]) { j = t; break; } }
        wbuf[i] = ldw(wp.p[SRC[j]], i - C2[j], isbf);
        return;
    }
    int i = b * 256 + threadIdx.x;
    if (i < 6144) {   // cw2r[c2][k'=dk*32+ci]
        int c2 = i / 96, k = i - c2 * 96, s = k >> 5, ci = k & 31;
        cw2r[i] = f2b(ldw(wp.p[2], c2 * 96 + ci * 3 + s, isbf));
    }
    if (i < 16384) {  // W0t / Wa1t, coalesced reads
        int k = i >> 8, c = i & 255;
        W0t[c * 64 + k] = f2b(ldw(wp.p[4], k * 256 + c, isbf));
        int ka = i >> 6, ca = i & 63;
        Wa1t[ca * 256 + ka] = f2b(ldw(wp.p[16], ka * 64 + ca, isbf));
    }
    if (i < 65536) {  // W1t
        int k = i >> 8, c = i & 255;
        W1t[c * 256 + k] = f2b(ldw(wp.p[8], k * 256 + c, isbf));
    }
    if (i < NEDGE + NNODE) {   // dst histogram (counts pre-zeroed by memset)
        bool ei64 = probe_ei64(ei);
        int dst;
        if (i < NEDGE) dst = ei64 ? ei[2 * (NEDGE + i)] : ei[NEDGE + i];
        else dst = i - NEDGE;
        if (dst >= 0 && dst < NNODE) atomicAdd(&counts[dst], 1);
    }
}

// ---------------- parallel scan ----------------
__global__ __launch_bounds__(256) void k_scan1(const int* __restrict__ counts,
        int* __restrict__ cur, int* __restrict__ bsum) {
    __shared__ int buf[256];
    int tid = threadIdx.x;
    int i = blockIdx.x * 256 + tid;
    int v = (i < NNODE) ? counts[i] : 0;
    buf[tid] = v;
    __syncthreads();
    for (int off = 1; off < 256; off <<= 1) {
        int t = (tid >= off) ? buf[tid - off] : 0;
        __syncthreads();
        buf[tid] += t;
        __syncthreads();
    }
    if (i < NNODE) cur[i] = buf[tid];
    if (tid == 255) bsum[blockIdx.x] = buf[255];
}
__global__ __launch_bounds__(256) void k_scan3(const int* __restrict__ counts,
        int* __restrict__ cur, const int* __restrict__ bsum, int* __restrict__ row_ptr) {
    __shared__ int pre_s;
    int tid = threadIdx.x;
    if (tid == 0) {
        int s = 0;
        for (int j = 0; j < blockIdx.x; ++j) s += bsum[j];
        pre_s = s;
    }
    __syncthreads();
    int i = blockIdx.x * 256 + tid;
    if (i >= NNODE) return;
    int incl = cur[i] + pre_s;
    row_ptr[i + 1] = incl;
    cur[i] = incl - counts[i];
    if (i == 0) row_ptr[0] = 0;
}

// ---- fused temporal conv + CSR fill; wave-owns-n-tile, parity-dbuf hs, 1 bar/node ----
#define HSTR 40
#define WSTR 96
#define FILL_BLK 665
__global__ __launch_bounds__(256) void k_conv(const void* __restrict__ xsrc,
        const float* __restrict__ wbuf, const u16* __restrict__ cw2r,
        u16* __restrict__ featb, const int* __restrict__ ei,
        int* __restrict__ cur, int* __restrict__ col_src) {
    __shared__ __align__(16) float xs[4][132];
    __shared__ float w1s[96], b1s[32], b2s[64];
    __shared__ __align__(16) u16 w2s[64 * WSTR];
    __shared__ __align__(16) u16 hs[2][66 * HSTR];   // parity double-buffer

    bool isbf = probe_x_bf16(xsrc);
    int tid = threadIdx.x;
    int wave = tid >> 6, lane = tid & 63;
    int node0 = blockIdx.x * 4;

    {
        int j = tid >> 6, p = (tid & 63) * 2;
        if (isbf) {
            u32 w = ((const u32*)xsrc)[(size_t)node0 * 64 + tid];
            xs[j][1 + p] = u2f((u16)(w & 0xFFFF));
            xs[j][2 + p] = u2f((u16)(w >> 16));
        } else {
            float2 w = ((const float2*)xsrc)[(size_t)node0 * 64 + tid];
            xs[j][1 + p] = w.x;
            xs[j][2 + p] = w.y;
        }
    }
    if (tid < 8) xs[tid >> 1][(tid & 1) ? 129 : 0] = 0.f;
    if (tid < 96) w1s[tid] = wbuf[S_CW1 + tid];
    if (tid < 32) b1s[tid] = wbuf[S_CB1 + tid];
    if (tid < 64) b2s[tid] = wbuf[S_CB2 + tid];
    for (int i = tid; i < 768; i += 256)
        ((short8*)w2s)[i] = ((const short8*)cw2r)[i];   // identity: WSTR == 96
    // zero pad rows (t=-1, t=64) of BOTH hs buffers: 4 segments x 32 channels
    if (tid < 128) {
        int bf = tid >> 6, seg = (tid >> 5) & 1, ch = tid & 31;
        hs[bf][seg ? (65 * HSTR + ch) : ch] = 0;
    }
    __syncthreads();

    int d = tid & 15, uu = tid >> 4;
    float wa0 = w1s[6 * d + 0], wa1 = w1s[6 * d + 1], wa2 = w1s[6 * d + 2];
    float wb0 = w1s[6 * d + 3], wb1 = w1s[6 * d + 4], wb2 = w1s[6 * d + 5];
    float ba = b1s[2 * d], bb = b1s[2 * d + 1];
    int m = lane & 15, q = lane >> 4;
    int n = wave * 16 + m;             // this wave's c2 columns
    float b2v = b2s[n];

    for (int j = 0; j < 4; ++j) {
        u16* hw = &hs[j & 1][0];
        const float* xr = &xs[j][0];
        #pragma unroll
        for (int it = 0; it < 4; ++it) {
            int u = uu + 16 * it;
            int t0 = 2 * u;
            float x0 = xr[t0], x1 = xr[t0 + 1], x2 = xr[t0 + 2], x3 = xr[t0 + 3];
            f32x2 A = {x0, x1}, Bv = {x1, x2}, Cv = {x2, x3};
            f32x2 va = {ba, ba}; va += wa0 * A; va += wa1 * Bv; va += wa2 * Cv;
            f32x2 vb = {bb, bb}; vb += wb0 * A; vb += wb1 * Bv; vb += wb2 * Cv;
            float ha = fmaxf(fmaxf(va.x, va.y), 0.f);
            float hb = fmaxf(fmaxf(vb.x, vb.y), 0.f);
            __hip_bfloat162 hp2 = __float22bfloat162_rn(make_float2(ha, hb));
            u32 pack; __builtin_memcpy(&pack, &hp2, 4);
            *(u32*)&hw[(u + 1) * HSTR + 2 * d] = pack;
        }
        __syncthreads();   // the ONLY barrier per node (parity buffer handles WAR)

        // MFMA: wave owns n-tile; all 4 m-tiles in-register -> no cross-wave reduce
        f32x4 accm0 = {0.f,0.f,0.f,0.f}, accm1 = {0.f,0.f,0.f,0.f};
        f32x4 accm2 = {0.f,0.f,0.f,0.f}, accm3 = {0.f,0.f,0.f,0.f};
        #pragma unroll
        for (int s = 0; s < 3; ++s) {
            short8 bfr = *(const short8*)&w2s[n * WSTR + s * 32 + q * 8];
            short8 a0 = *(const short8*)&hw[(0 * 16 + m + s) * HSTR + q * 8];
            short8 a1 = *(const short8*)&hw[(1 * 16 + m + s) * HSTR + q * 8];
            short8 a2 = *(const short8*)&hw[(2 * 16 + m + s) * HSTR + q * 8];
            short8 a3 = *(const short8*)&hw[(3 * 16 + m + s) * HSTR + q * 8];
            accm0 = __builtin_amdgcn_mfma_f32_16x16x32_bf16(a0, bfr, accm0, 0, 0, 0);
            accm1 = __builtin_amdgcn_mfma_f32_16x16x32_bf16(a1, bfr, accm1, 0, 0, 0);
            accm2 = __builtin_amdgcn_mfma_f32_16x16x32_bf16(a2, bfr, accm2, 0, 0, 0);
            accm3 = __builtin_amdgcn_mfma_f32_16x16x32_bf16(a3, bfr, accm3, 0, 0, 0);
        }
        float scl = prelu(accm0[0] + b2v) + prelu(accm0[1] + b2v)
                  + prelu(accm0[2] + b2v) + prelu(accm0[3] + b2v);
        scl += prelu(accm1[0] + b2v) + prelu(accm1[1] + b2v)
             + prelu(accm1[2] + b2v) + prelu(accm1[3] + b2v);
        scl += prelu(accm2[0] + b2v) + prelu(accm2[1] + b2v)
             + prelu(accm2[2] + b2v) + prelu(accm2[3] + b2v);
        scl += prelu(accm3[0] + b2v) + prelu(accm3[1] + b2v)
             + prelu(accm3[2] + b2v) + prelu(accm3[3] + b2v);
        scl += __shfl_xor(scl, 16, 64);
        scl += __shfl_xor(scl, 32, 64);
        if (lane < 16) {
            int node = node0 + j;
            int bb2 = node / NNODE, nn = node - bb2 * NNODE;
            featb[((size_t)nn * 4 + bb2) * 64 + wave * 16 + lane] = f2b(scl * (1.f / 64.f));
        }
    }

    // ---- CSR fill slice (blocks < FILL_BLK) ----
    if (blockIdx.x < FILL_BLK) {
        bool ei64 = probe_ei64(ei);
        int e = blockIdx.x * 256 + tid;
        if (e < NEDGE + NNODE) {
            int src, dst;
            if (e < NEDGE) {
                if (ei64) { src = ei[2 * e]; dst = ei[2 * (NEDGE + e)]; }
                else      { src = ei[e];     dst = ei[NEDGE + e]; }
            } else {
                src = dst = e - NEDGE;
            }
            if (dst >= 0 && dst < NNODE) {
                int pos = atomicAdd(&cur[dst], 1);
                if (pos >= 0 && pos < NEDGE + NNODE) col_src[pos] = src;
            }
        }
    }
}

// ------ zero-LDS MFMA GEMM (MT=1), fused attention scores ------
template<int K>
__global__ __launch_bounds__(256) void k_gemm(const u16* __restrict__ A,
        const u16* __restrict__ Wt, const float* __restrict__ att_s_w,
        const float* __restrict__ att_d_w, u16* __restrict__ outb,
        float* __restrict__ a_s, float* __restrict__ a_d) {
    int wave = threadIdx.x >> 6, lane = threadIdx.x & 63;
    int row0 = (blockIdx.x * 4 + wave) * 16;
    int m = lane & 15, q = lane >> 4;
    f32x4 acc[16];
    #pragma unroll
    for (int nt = 0; nt < 16; ++nt) acc[nt] = {0.f, 0.f, 0.f, 0.f};
    for (int kc = 0; kc < K; kc += 32) {
        short8 a = *(const short8*)&A[(size_t)(row0 + m) * K + kc + q * 8];
        #pragma unroll
        for (int nt = 0; nt < 16; ++nt) {
            short8 b = *(const short8*)&Wt[(size_t)(nt * 16 + m) * K + kc + q * 8];
            acc[nt] = __builtin_amdgcn_mfma_f32_16x16x32_bf16(a, b, acc[nt], 0, 0, 0);
        }
    }
    #pragma unroll
    for (int nt = 0; nt < 16; ++nt) {
        #pragma unroll
        for (int r = 0; r < 4; ++r)
            outb[(size_t)(row0 + q * 4 + r) * 256 + nt * 16 + m] = f2b(acc[nt][r]);
    }
    float sh_s[4][4] = {{0}}, sh_d[4][4] = {{0}};
    #pragma unroll
    for (int nt = 0; nt < 16; ++nt) {
        int h = nt >> 2;
        int cc = (nt & 3) * 16 + m;
        float asw = att_s_w[h * 64 + cc];
        float adw = att_d_w[h * 64 + cc];
        #pragma unroll
        for (int r = 0; r < 4; ++r) {
            sh_s[h][r] += acc[nt][r] * asw;
            sh_d[h][r] += acc[nt][r] * adw;
        }
    }
    #pragma unroll
    for (int off = 1; off < 16; off <<= 1) {
        #pragma unroll
        for (int h = 0; h < 4; ++h)
            #pragma unroll
            for (int r = 0; r < 4; ++r) {
                sh_s[h][r] += __shfl_xor(sh_s[h][r], off, 64);
                sh_d[h][r] += __shfl_xor(sh_d[h][r], off, 64);
            }
    }
    if (m == 0) {
        #pragma unroll
        for (int r = 0; r < 4; ++r) {
            int row = row0 + q * 4 + r;
            float4 vs = {sh_s[0][r], sh_s[1][r], sh_s[2][r], sh_s[3][r]};
            float4 vd = {sh_d[0][r], sh_d[1][r], sh_d[2][r], sh_d[3][r]};
            *(float4*)&a_s[(size_t)row * 4] = vs;
            *(float4*)&a_d[(size_t)row * 4] = vd;
        }
    }
}

// ---------------- GAT aggregation: pass-2 chunk-4 MLP unroll, NAMED scalars only ------
__global__ __launch_bounds__(256) void k_agg(const u16* __restrict__ xlb,
        const float* __restrict__ a_s, const float* __restrict__ a_d,
        const int* __restrict__ row_ptr, const int* __restrict__ col_src,
        const float* __restrict__ bias, u16* __restrict__ gb_out) {
    int wave = threadIdx.x >> 6, lane = threadIdx.x & 63;
    int dst = blockIdx.x * 2 + (wave >> 1);
    int bp = (wave & 1) * 2;
    int beg = row_ptr[dst], end = row_ptr[dst + 1];

    // pass 1: exact max per (b,h); 8-way edge split across replica groups
    int c = lane & 7, g = lane >> 3;
    int bc = bp + (c >> 2), hc = c & 3;
    float adv1 = a_d[(size_t)dst * 16 + bc * 4 + hc];
    float mloc = -INFINITY;
    for (int i = beg + g; i < end; i += 8) {
        int src = min(max(col_src[i], 0), NNODE - 1);
        float e = a_s[(size_t)src * 16 + bc * 4 + hc] + adv1;
        e = (e >= 0.f) ? e : 0.2f * e;
        mloc = fmaxf(mloc, e);
    }
    mloc = fmaxf(mloc, __shfl_xor(mloc, 8, 64));
    mloc = fmaxf(mloc, __shfl_xor(mloc, 16, 64));
    mloc = fmaxf(mloc, __shfl_xor(mloc, 32, 64));

    int bl = lane >> 5;
    int s = lane & 31;
    int h = s >> 3;
    int b = bp + bl;
    float mv = __shfl(mloc, bl * 4 + h, 64);

    // pass 2: chunk-4 unroll — 4 col_src (contiguous) + 4 a_s + 4 xlb loads in flight.
    float advh = a_d[(size_t)dst * 16 + b * 4 + h];
    float acc[8];
    #pragma unroll
    for (int k = 0; k < 8; ++k) acc[k] = 0.f;
    float l = 0.f;

    int asoff = b * 4 + h;
    int i = beg;
    for (; i + 4 <= end; i += 4) {
        int s0 = min(max(col_src[i], 0), NNODE - 1);
        int s1 = min(max(col_src[i + 1], 0), NNODE - 1);
        int s2 = min(max(col_src[i + 2], 0), NNODE - 1);
        int s3 = min(max(col_src[i + 3], 0), NNODE - 1);
        float a0 = a_s[(size_t)s0 * 16 + asoff];
        float a1 = a_s[(size_t)s1 * 16 + asoff];
        float a2 = a_s[(size_t)s2 * 16 + asoff];
        float a3 = a_s[(size_t)s3 * 16 + asoff];
        short8 x0 = *(const short8*)&xlb[((size_t)s0 * 4 + b) * 256 + s * 8];
        short8 x1 = *(const short8*)&xlb[((size_t)s1 * 4 + b) * 256 + s * 8];
        short8 x2 = *(const short8*)&xlb[((size_t)s2 * 4 + b) * 256 + s * 8];
        short8 x3 = *(const short8*)&xlb[((size_t)s3 * 4 + b) * 256 + s * 8];
        float e0 = a0 + advh; e0 = (e0 >= 0.f) ? e0 : 0.2f * e0;
        float p0 = __expf(e0 - mv); l += p0;
        #pragma unroll
        for (int k = 0; k < 8; ++k) acc[k] += p0 * u2f((u16)x0[k]);
        float e1 = a1 + advh; e1 = (e1 >= 0.f) ? e1 : 0.2f * e1;
        float p1 = __expf(e1 - mv); l += p1;
        #pragma unroll
        for (int k = 0; k < 8; ++k) acc[k] += p1 * u2f((u16)x1[k]);
        float e2 = a2 + advh; e2 = (e2 >= 0.f) ? e2 : 0.2f * e2;
        float p2 = __expf(e2 - mv); l += p2;
        #pragma unroll
        for (int k = 0; k < 8; ++k) acc[k] += p2 * u2f((u16)x2[k]);
        float e3 = a3 + advh; e3 = (e3 >= 0.f) ? e3 : 0.2f * e3;
        float p3 = __expf(e3 - mv); l += p3;
        #pragma unroll
        for (int k = 0; k < 8; ++k) acc[k] += p3 * u2f((u16)x3[k]);
    }
    for (; i < end; ++i) {
        int s0 = min(max(col_src[i], 0), NNODE - 1);
        float a0 = a_s[(size_t)s0 * 16 + asoff];
        short8 x0 = *(const short8*)&xlb[((size_t)s0 * 4 + b) * 256 + s * 8];
        float e0 = a0 + advh; e0 = (e0 >= 0.f) ? e0 : 0.2f * e0;
        float p0 = __expf(e0 - mv); l += p0;
        #pragma unroll
        for (int k = 0; k < 8; ++k) acc[k] += p0 * u2f((u16)x0[k]);
    }
    float rl = 1.f / (l + 1e-16f);
    short8 o;
    #pragma unroll
    for (int k = 0; k < 8; ++k)
        o[k] = (short)f2b(prelu(acc[k] * rl + bias[s * 8 + k]));
    *(short8*)&gb_out[((size_t)dst * 4 + b) * 256 + s * 8] = o;
}

// ---------------- attribution head (blocks <625) + pooled sum (blocks >=625) ----------
__global__ __launch_bounds__(256) void k_attrpool(const u16* __restrict__ gb,
        const u16* __restrict__ Wa1t, const float* __restrict__ wbuf,
        float* __restrict__ out, float* __restrict__ pooled) {
    if (blockIdx.x >= 625) {   // pool part, n-loop unrolled x4 (independent loads)
        int pb = blockIdx.x - 625;
        int b = pb >> 6;
        int chunk = pb & 63;
        int cch = threadIdx.x;
        int n0 = chunk * 157;
        int n1 = min(NNODE, n0 + 157);
        float acc = 0.f;
        int n = n0;
        for (; n + 4 <= n1; n += 4) {
            float v0 = u2f(gb[((size_t)n * 4 + b) * 256 + cch]);
            float v1 = u2f(gb[((size_t)(n + 1) * 4 + b) * 256 + cch]);
            float v2 = u2f(gb[((size_t)(n + 2) * 4 + b) * 256 + cch]);
            float v3 = u2f(gb[((size_t)(n + 3) * 4 + b) * 256 + cch]);
            acc += v0; acc += v1; acc += v2; acc += v3;
        }
        for (; n < n1; ++n)
            acc += u2f(gb[((size_t)n * 4 + b) * 256 + cch]);
        atomicAdd(&pooled[b * 256 + cch], acc);
        return;
    }
    int wave = threadIdx.x >> 6, lane = threadIdx.x & 63;
    int row0 = (blockIdx.x * 4 + wave) * 16;
    int m = lane & 15, q = lane >> 4;
    f32x4 acc[4];
    #pragma unroll
    for (int nt = 0; nt < 4; ++nt) acc[nt] = {0.f, 0.f, 0.f, 0.f};
    for (int kc = 0; kc < 256; kc += 32) {
        short8 a = *(const short8*)&gb[(size_t)(row0 + m) * 256 + kc + q * 8];
        #pragma unroll
        for (int nt = 0; nt < 4; ++nt) {
            short8 b = *(const short8*)&Wa1t[(size_t)(nt * 16 + m) * 256 + kc + q * 8];
            acc[nt] = __builtin_amdgcn_mfma_f32_16x16x32_bf16(a, b, acc[nt], 0, 0, 0);
        }
    }
    float part[4] = {0, 0, 0, 0};
    #pragma unroll
    for (int nt = 0; nt < 4; ++nt) {
        int col = nt * 16 + m;
        float ba1v = wbuf[S_BA1 + col];
        float wa2v = wbuf[S_WA2 + col];
        #pragma unroll
        for (int r = 0; r < 4; ++r)
            part[r] += prelu(acc[nt][r] + ba1v) * wa2v;
    }
    #pragma unroll
    for (int off = 1; off < 16; off <<= 1) {
        #pragma unroll
        for (int r = 0; r < 4; ++r)
            part[r] += __shfl_xor(part[r], off, 64);
    }
    if (m == 0) {
        float ba2v = wbuf[S_BA2];
        #pragma unroll
        for (int r = 0; r < 4; ++r) {
            int row = row0 + q * 4 + r;
            int n = row >> 2, b = row & 3;
            float v = part[r] + ba2v;
            out[8 + b * NNODE + n] = 1.f / (1.f + __expf(-v));
        }
    }
}

// ---------------- classification head (blocks 0-3) + diagnostics (block 4) ----------
__global__ __launch_bounds__(128) void k_logits(const float* __restrict__ pooled,
        const float* __restrict__ wbuf, const void* __restrict__ Wc1p,
        float* __restrict__ out,
        const u16* __restrict__ featb, const u16* __restrict__ gb,
        const int* __restrict__ row_ptr, const int* __restrict__ ei,
        const void* __restrict__ xsrc, int hostbad) {
    int tid = threadIdx.x;
    bool isbf = probe_x_bf16(xsrc);
    if (blockIdx.x == 4) {   // sampled diagnostics
        __shared__ float red[128];
        bool ei64 = probe_ei64(ei);
        float mx[2] = {0.f, 0.f};
        const u16* bufs[2] = {featb, gb};
        for (int qq = 0; qq < 2; ++qq) {
            const u16* p = bufs[qq];
            float m = 0.f;
            for (int i = tid; i < 2048; i += 128) {
                float v = u2f(p[i]);
                if (v != v) m = 1e30f;
                m = fmaxf(m, fabsf(v));
            }
            red[tid] = m;
            __syncthreads();
            for (int s2 = 64; s2 > 0; s2 >>= 1) {
                if (tid < s2) red[tid] = fmaxf(red[tid], red[tid + s2]);
                __syncthreads();
            }
            mx[qq] = red[0];
            __syncthreads();
        }
        if (tid == 0) {
            int fb = (mx[0] > 1e8f || mx[0] < 1e-6f) ? 1 : 0;
            int gbad = (mx[1] > 1e8f || mx[1] < 1e-6f) ? 1 : 0;
            int cb = (row_ptr[NNODE] != NEDGE + NNODE) ? 1 : 0;
            int code = 100 * fb + 400 * gbad + 800 * cb + 6400 * hostbad;
            if (code) {
                code += 1600 * (isbf ? 0 : 1);
                code += 3200 * (ei64 ? 1 : 0);
                for (int j = 0; j < 8; ++j) out[j] = (float)code;
            }
        }
        return;
    }
    __shared__ float pm[256];
    __shared__ float red4[4];
    int b = blockIdx.x;
    pm[tid] = pooled[b * 256 + tid] * (1.f / NNODE);
    pm[tid + 128] = pooled[b * 256 + tid + 128] * (1.f / NNODE);
    __syncthreads();
    float acc = wbuf[S_BC1 + tid];
    if (isbf) {
        const u16* w = (const u16*)Wc1p;
        #pragma unroll 4
        for (int k = 0; k < 256; ++k)
            acc += pm[k] * u2f(w[k * 128 + tid]);
    } else {
        const float* w = (const float*)Wc1p;
        #pragma unroll 4
        for (int k = 0; k < 256; ++k)
            acc += pm[k] * w[k * 128 + tid];
    }
    float hv = prelu(acc);
    float p0 = hv * wbuf[S_WC2 + tid * 2];
    float p1 = hv * wbuf[S_WC2 + tid * 2 + 1];
    #pragma unroll
    for (int off = 32; off > 0; off >>= 1) {
        p0 += __shfl_xor(p0, off, 64);
        p1 += __shfl_xor(p1, off, 64);
    }
    int wv = tid >> 6, lane = tid & 63;
    if (lane == 0) { red4[wv * 2] = p0; red4[wv * 2 + 1] = p1; }
    __syncthreads();
    if (tid < 2)
        out[b * 2 + tid] = red4[tid] + red4[2 + tid] + wbuf[S_BC2 + tid];
}

extern "C" void kernel_launch(void* const* d_in, const int* in_sizes, int n_in,
                              void* d_out, int out_size, void* d_ws, size_t ws_size,
                              hipStream_t stream) {
    const void* x  = d_in[0];
    const int*  ei = (const int*)d_in[1];
    float* out = (float*)d_out;

    WPtrs wp;
    for (int j = 0; j < 20; ++j) wp.p[j] = d_in[j + 2];

    char* ws = (char*)d_ws;
    size_t off = 0;
    auto alloc = [&](size_t bytes) -> void* {
        void* p = ws + off;
        off += (bytes + 255) & ~(size_t)255;
        return p;
    };
    float* wbuf    = (float*)alloc((size_t)S_TOTAL * 4);
    u16*   featb   = (u16*)  alloc((size_t)BATCH * NNODE * 64 * 2);
    u16*   xlb     = (u16*)  alloc((size_t)BATCH * NNODE * 256 * 2);
    u16*   gb      = (u16*)  alloc((size_t)BATCH * NNODE * 256 * 2);
    float* a_s     = (float*)alloc((size_t)BATCH * NNODE * 4 * 4);
    float* a_d     = (float*)alloc((size_t)BATCH * NNODE * 4 * 4);
    u16*   cw2r    = (u16*)alloc(6144 * 2);
    u16*   W0t     = (u16*)alloc(16384 * 2);
    u16*   W1t     = (u16*)alloc(65536 * 2);
    u16*   Wa1t    = (u16*)alloc(16384 * 2);
    // counts and pooled ADJACENT: one memset zeroes both
    int*   counts  = (int*)alloc(NNODE * 4);           // padded to 40192
    float* pooled  = (float*)alloc(BATCH * 256 * 4);   // 4096
    int*   row_ptr = (int*)alloc((NNODE + 1) * 4);
    int*   cur     = (int*)alloc(NNODE * 4);
    int*   col_src = (int*)alloc((NEDGE + NNODE) * 4);
    int*   bsum    = (int*)alloc(64 * 4);
    (void)ws_size; (void)out_size;

    int hostbad = (n_in != 22 || in_sizes[0] != BATCH * NNODE * TLEN ||
                   in_sizes[1] != 2 * NEDGE) ? 1 : 0;

    hipMemsetAsync(counts, 0, 40192 + 4096, stream);

    k_pre<<<PRE_TBLK + 9, 256, 0, stream>>>(wp, x, ei, wbuf, cw2r, W0t, W1t, Wa1t, counts);
    k_scan1<<<40, 256, 0, stream>>>(counts, cur, bsum);
    k_scan3<<<40, 256, 0, stream>>>(counts, cur, bsum, row_ptr);

    // conv + CSR fill fused
    k_conv<<<BATCH * NNODE / 4, 256, 0, stream>>>(x, wbuf, cw2r, featb, ei, cur, col_src);

    // GAT layer 0
    k_gemm<64><<<BATCH * NNODE / 64, 256, 0, stream>>>(featb, W0t,
            wbuf + S_AS0, wbuf + S_AD0, xlb, a_s, a_d);
    k_agg<<<NNODE / 2, 256, 0, stream>>>(xlb, a_s, a_d, row_ptr, col_src, wbuf + S_B0, gb);

    // GAT layer 1
    k_gemm<256><<<BATCH * NNODE / 64, 256, 0, stream>>>(gb, W1t,
            wbuf + S_AS1, wbuf + S_AD1, xlb, a_s, a_d);
    k_agg<<<NNODE / 2, 256, 0, stream>>>(xlb, a_s, a_d, row_ptr, col_src, wbuf + S_B1, gb);

    // heads
    k_attrpool<<<625 + 256, 256, 0, stream>>>(gb, Wa1t, wbuf, out, pooled);
    k_logits<<<5, 128, 0, stream>>>(pooled, wbuf, wp.p[12], out, featb, gb, row_ptr, ei, x, hostbad);
}

// Round 16
// 402.539 us; speedup vs baseline: 4.1169x; 1.0295x over previous
//
#include <hip/hip_runtime.h>
#include <hip/hip_bf16.h>
#include <math.h>

typedef __hip_bfloat16 bf16;
typedef unsigned short u16;
typedef unsigned int u32;
typedef __attribute__((ext_vector_type(8))) short short8;
typedef __attribute__((ext_vector_type(4))) float f32x4;
typedef __attribute__((ext_vector_type(2))) float f32x2;

#define BATCH 4
#define NNODE 10000
#define TLEN 128
#define NEDGE 160000
#define GDIM 256
#define NHEAD 4

// small-weight fp32 staging offsets (everything except W0/W1/Wa1/Wc1)
#define S_CW1 0
#define S_CB1 96
#define S_CB2 128
#define S_AS0 192
#define S_AD0 448
#define S_B0  704
#define S_AS1 960
#define S_AD1 1216
#define S_B1  1472
#define S_BC1 1728
#define S_WC2 1856
#define S_BC2 2112
#define S_BA1 2114
#define S_WA2 2178
#define S_BA2 2242
#define S_TOTAL 2243

__device__ __forceinline__ float prelu(float v) { return 0.5f * (v + fabsf(v)); }
__device__ __forceinline__ u16 f2b(float f) {
    union { float f; u32 u; } v; v.f = f;
    u32 r = v.u + 0x7FFF + ((v.u >> 16) & 1);
    return (u16)(r >> 16);
}
__device__ __forceinline__ float u2f(u16 u) {
    union { u32 u; float f; } v; v.u = ((u32)u) << 16;
    return v.f;
}
__device__ __forceinline__ float ldw(const void* p, int off, bool isbf) {
    return isbf ? u2f(((const u16*)p)[off]) : ((const float*)p)[off];
}

// per-wave inline dtype probes (all waves compute identical results)
__device__ __forceinline__ bool probe_x_bf16(const void* xsrc) {
    int lane = threadIdx.x & 63;
    u16 h = ((const u16*)xsrc)[2 * lane];
    int e = (h >> 7) & 0xFF;
    unsigned long long m = __ballot(e >= 117 && e <= 130);
    return __popcll(m) >= 32;
}
__device__ __forceinline__ bool probe_ei64(const int* ei) {
    int lane = threadIdx.x & 63;
    int v = ei[2 * lane + 1];
    unsigned long long m = __ballot(v == 0);
    return __popcll(m) >= 56;
}

struct WPtrs { const void* p[20]; };

// ------ merged: bf16 transposes + dst histogram + small-weight fp32 staging ------
#define PRE_TBLK 665   // covers max(65536, 170000) indices
__global__ __launch_bounds__(256) void k_pre(WPtrs wp, const void* __restrict__ xsrc,
        const int* __restrict__ ei, float* __restrict__ wbuf,
        u16* __restrict__ cw2r, u16* __restrict__ W0t, u16* __restrict__ W1t,
        u16* __restrict__ Wa1t, int* __restrict__ counts) {
    bool isbf = probe_x_bf16(xsrc);
    int b = blockIdx.x;
    if (b >= PRE_TBLK) {   // small-weight staging (9 blocks)
        const int C2[16] = {0,96,128,192,448,704,960,1216,1472,1728,1856,2112,
                            2114,2178,2242,2243};
        const int SRC[15] = {0,1,3,5,6,7,9,10,11,13,14,15,17,18,19};
        int i = (b - PRE_TBLK) * 256 + threadIdx.x;
        if (i >= S_TOTAL) return;
        int j = 14;
        for (int t = 0; t < 15; ++t) { if (i < C2[t + 1]) { j = t; break; } }
        wbuf[i] = ldw(wp.p[SRC[j]], i - C2[j], isbf);
        return;
    }
    int i = b * 256 + threadIdx.x;
    if (i < 6144) {   // cw2r[c2][k'=dk*32+ci]
        int c2 = i / 96, k = i - c2 * 96, s = k >> 5, ci = k & 31;
        cw2r[i] = f2b(ldw(wp.p[2], c2 * 96 + ci * 3 + s, isbf));
    }
    if (i < 16384) {  // W0t / Wa1t, coalesced reads
        int k = i >> 8, c = i & 255;
        W0t[c * 64 + k] = f2b(ldw(wp.p[4], k * 256 + c, isbf));
        int ka = i >> 6, ca = i & 63;
        Wa1t[ca * 256 + ka] = f2b(ldw(wp.p[16], ka * 64 + ca, isbf));
    }
    if (i < 65536) {  // W1t
        int k = i >> 8, c = i & 255;
        W1t[c * 256 + k] = f2b(ldw(wp.p[8], k * 256 + c, isbf));
    }
    if (i < NEDGE + NNODE) {   // dst histogram (counts pre-zeroed by memset)
        bool ei64 = probe_ei64(ei);
        int dst;
        if (i < NEDGE) dst = ei64 ? ei[2 * (NEDGE + i)] : ei[NEDGE + i];
        else dst = i - NEDGE;
        if (dst >= 0 && dst < NNODE) atomicAdd(&counts[dst], 1);
    }
}

// ---------------- parallel scan ----------------
__global__ __launch_bounds__(256) void k_scan1(const int* __restrict__ counts,
        int* __restrict__ cur, int* __restrict__ bsum) {
    __shared__ int buf[256];
    int tid = threadIdx.x;
    int i = blockIdx.x * 256 + tid;
    int v = (i < NNODE) ? counts[i] : 0;
    buf[tid] = v;
    __syncthreads();
    for (int off = 1; off < 256; off <<= 1) {
        int t = (tid >= off) ? buf[tid - off] : 0;
        __syncthreads();
        buf[tid] += t;
        __syncthreads();
    }
    if (i < NNODE) cur[i] = buf[tid];
    if (tid == 255) bsum[blockIdx.x] = buf[255];
}
__global__ __launch_bounds__(256) void k_scan3(const int* __restrict__ counts,
        int* __restrict__ cur, const int* __restrict__ bsum, int* __restrict__ row_ptr) {
    __shared__ int pre_s;
    int tid = threadIdx.x;
    if (tid == 0) {
        int s = 0;
        for (int j = 0; j < blockIdx.x; ++j) s += bsum[j];
        pre_s = s;
    }
    __syncthreads();
    int i = blockIdx.x * 256 + tid;
    if (i >= NNODE) return;
    int incl = cur[i] + pre_s;
    row_ptr[i + 1] = incl;
    cur[i] = incl - counts[i];
    if (i == 0) row_ptr[0] = 0;
}

// ---- fused temporal conv + CSR fill; wave-owns-n-tile, parity-dbuf hs,
// B-fragments hoisted in REGISTERS from L2-resident cw2r (no w2s LDS) ----
#define HSTR 40
#define FILL_BLK 665
__global__ __launch_bounds__(256) void k_conv(const void* __restrict__ xsrc,
        const float* __restrict__ wbuf, const u16* __restrict__ cw2r,
        u16* __restrict__ featb, const int* __restrict__ ei,
        int* __restrict__ cur, int* __restrict__ col_src) {
    __shared__ __align__(16) float xs[4][132];
    __shared__ float w1s[96], b1s[32], b2s[64];
    __shared__ __align__(16) u16 hs[2][66 * HSTR];   // parity double-buffer

    bool isbf = probe_x_bf16(xsrc);
    int tid = threadIdx.x;
    int wave = tid >> 6, lane = tid & 63;
    int node0 = blockIdx.x * 4;

    int m = lane & 15, q = lane >> 4;
    int n = wave * 16 + m;             // this wave's c2 columns
    // B-fragments: loop-invariant, from L2 (all blocks share 12 KB)
    short8 bfr0 = *(const short8*)&cw2r[n * 96 + 0 * 32 + q * 8];
    short8 bfr1 = *(const short8*)&cw2r[n * 96 + 1 * 32 + q * 8];
    short8 bfr2 = *(const short8*)&cw2r[n * 96 + 2 * 32 + q * 8];

    {
        int j = tid >> 6, p = (tid & 63) * 2;
        if (isbf) {
            u32 w = ((const u32*)xsrc)[(size_t)node0 * 64 + tid];
            xs[j][1 + p] = u2f((u16)(w & 0xFFFF));
            xs[j][2 + p] = u2f((u16)(w >> 16));
        } else {
            float2 w = ((const float2*)xsrc)[(size_t)node0 * 64 + tid];
            xs[j][1 + p] = w.x;
            xs[j][2 + p] = w.y;
        }
    }
    if (tid < 8) xs[tid >> 1][(tid & 1) ? 129 : 0] = 0.f;
    if (tid < 96) w1s[tid] = wbuf[S_CW1 + tid];
    if (tid < 32) b1s[tid] = wbuf[S_CB1 + tid];
    if (tid < 64) b2s[tid] = wbuf[S_CB2 + tid];
    // zero pad rows (t=-1, t=64) of BOTH hs buffers: 4 segments x 32 channels
    if (tid < 128) {
        int bf = tid >> 6, seg = (tid >> 5) & 1, ch = tid & 31;
        hs[bf][seg ? (65 * HSTR + ch) : ch] = 0;
    }
    __syncthreads();

    int d = tid & 15, uu = tid >> 4;
    float wa0 = w1s[6 * d + 0], wa1 = w1s[6 * d + 1], wa2 = w1s[6 * d + 2];
    float wb0 = w1s[6 * d + 3], wb1 = w1s[6 * d + 4], wb2 = w1s[6 * d + 5];
    float ba = b1s[2 * d], bb = b1s[2 * d + 1];
    float b2v = b2s[n];

    for (int j = 0; j < 4; ++j) {
        u16* hw = &hs[j & 1][0];
        const float* xr = &xs[j][0];
        #pragma unroll
        for (int it = 0; it < 4; ++it) {
            int u = uu + 16 * it;
            int t0 = 2 * u;
            float x0 = xr[t0], x1 = xr[t0 + 1], x2 = xr[t0 + 2], x3 = xr[t0 + 3];
            f32x2 A = {x0, x1}, Bv = {x1, x2}, Cv = {x2, x3};
            f32x2 va = {ba, ba}; va += wa0 * A; va += wa1 * Bv; va += wa2 * Cv;
            f32x2 vb = {bb, bb}; vb += wb0 * A; vb += wb1 * Bv; vb += wb2 * Cv;
            float ha = fmaxf(fmaxf(va.x, va.y), 0.f);
            float hb = fmaxf(fmaxf(vb.x, vb.y), 0.f);
            __hip_bfloat162 hp2 = __float22bfloat162_rn(make_float2(ha, hb));
            u32 pack; __builtin_memcpy(&pack, &hp2, 4);
            *(u32*)&hw[(u + 1) * HSTR + 2 * d] = pack;
        }
        __syncthreads();   // the ONLY barrier per node (parity buffer handles WAR)

        // MFMA: wave owns n-tile; all 4 m-tiles in-register
        f32x4 accm0 = {0.f,0.f,0.f,0.f}, accm1 = {0.f,0.f,0.f,0.f};
        f32x4 accm2 = {0.f,0.f,0.f,0.f}, accm3 = {0.f,0.f,0.f,0.f};
        {
            short8 a0 = *(const short8*)&hw[(0 * 16 + m + 0) * HSTR + q * 8];
            short8 a1 = *(const short8*)&hw[(1 * 16 + m + 0) * HSTR + q * 8];
            short8 a2 = *(const short8*)&hw[(2 * 16 + m + 0) * HSTR + q * 8];
            short8 a3 = *(const short8*)&hw[(3 * 16 + m + 0) * HSTR + q * 8];
            accm0 = __builtin_amdgcn_mfma_f32_16x16x32_bf16(a0, bfr0, accm0, 0, 0, 0);
            accm1 = __builtin_amdgcn_mfma_f32_16x16x32_bf16(a1, bfr0, accm1, 0, 0, 0);
            accm2 = __builtin_amdgcn_mfma_f32_16x16x32_bf16(a2, bfr0, accm2, 0, 0, 0);
            accm3 = __builtin_amdgcn_mfma_f32_16x16x32_bf16(a3, bfr0, accm3, 0, 0, 0);
        }
        {
            short8 a0 = *(const short8*)&hw[(0 * 16 + m + 1) * HSTR + q * 8];
            short8 a1 = *(const short8*)&hw[(1 * 16 + m + 1) * HSTR + q * 8];
            short8 a2 = *(const short8*)&hw[(2 * 16 + m + 1) * HSTR + q * 8];
            short8 a3 = *(const short8*)&hw[(3 * 16 + m + 1) * HSTR + q * 8];
            accm0 = __builtin_amdgcn_mfma_f32_16x16x32_bf16(a0, bfr1, accm0, 0, 0, 0);
            accm1 = __builtin_amdgcn_mfma_f32_16x16x32_bf16(a1, bfr1, accm1, 0, 0, 0);
            accm2 = __builtin_amdgcn_mfma_f32_16x16x32_bf16(a2, bfr1, accm2, 0, 0, 0);
            accm3 = __builtin_amdgcn_mfma_f32_16x16x32_bf16(a3, bfr1, accm3, 0, 0, 0);
        }
        {
            short8 a0 = *(const short8*)&hw[(0 * 16 + m + 2) * HSTR + q * 8];
            short8 a1 = *(const short8*)&hw[(1 * 16 + m + 2) * HSTR + q * 8];
            short8 a2 = *(const short8*)&hw[(2 * 16 + m + 2) * HSTR + q * 8];
            short8 a3 = *(const short8*)&hw[(3 * 16 + m + 2) * HSTR + q * 8];
            accm0 = __builtin_amdgcn_mfma_f32_16x16x32_bf16(a0, bfr2, accm0, 0, 0, 0);
            accm1 = __builtin_amdgcn_mfma_f32_16x16x32_bf16(a1, bfr2, accm1, 0, 0, 0);
            accm2 = __builtin_amdgcn_mfma_f32_16x16x32_bf16(a2, bfr2, accm2, 0, 0, 0);
            accm3 = __builtin_amdgcn_mfma_f32_16x16x32_bf16(a3, bfr2, accm3, 0, 0, 0);
        }
        float scl = prelu(accm0[0] + b2v) + prelu(accm0[1] + b2v)
                  + prelu(accm0[2] + b2v) + prelu(accm0[3] + b2v);
        scl += prelu(accm1[0] + b2v) + prelu(accm1[1] + b2v)
             + prelu(accm1[2] + b2v) + prelu(accm1[3] + b2v);
        scl += prelu(accm2[0] + b2v) + prelu(accm2[1] + b2v)
             + prelu(accm2[2] + b2v) + prelu(accm2[3] + b2v);
        scl += prelu(accm3[0] + b2v) + prelu(accm3[1] + b2v)
             + prelu(accm3[2] + b2v) + prelu(accm3[3] + b2v);
        scl += __shfl_xor(scl, 16, 64);
        scl += __shfl_xor(scl, 32, 64);
        if (lane < 16) {
            int node = node0 + j;
            int bb2 = node / NNODE, nn = node - bb2 * NNODE;
            featb[((size_t)nn * 4 + bb2) * 64 + wave * 16 + lane] = f2b(scl * (1.f / 64.f));
        }
    }

    // ---- CSR fill slice (blocks < FILL_BLK) ----
    if (blockIdx.x < FILL_BLK) {
        bool ei64 = probe_ei64(ei);
        int e = blockIdx.x * 256 + tid;
        if (e < NEDGE + NNODE) {
            int src, dst;
            if (e < NEDGE) {
                if (ei64) { src = ei[2 * e]; dst = ei[2 * (NEDGE + e)]; }
                else      { src = ei[e];     dst = ei[NEDGE + e]; }
            } else {
                src = dst = e - NEDGE;
            }
            if (dst >= 0 && dst < NNODE) {
                int pos = atomicAdd(&cur[dst], 1);
                if (pos >= 0 && pos < NEDGE + NNODE) col_src[pos] = src;
            }
        }
    }
}

// ------ zero-LDS MFMA GEMM (MT=1), fused attention scores ------
template<int K>
__global__ __launch_bounds__(256) void k_gemm(const u16* __restrict__ A,
        const u16* __restrict__ Wt, const float* __restrict__ att_s_w,
        const float* __restrict__ att_d_w, u16* __restrict__ outb,
        float* __restrict__ a_s, float* __restrict__ a_d) {
    int wave = threadIdx.x >> 6, lane = threadIdx.x & 63;
    int row0 = (blockIdx.x * 4 + wave) * 16;
    int m = lane & 15, q = lane >> 4;
    f32x4 acc[16];
    #pragma unroll
    for (int nt = 0; nt < 16; ++nt) acc[nt] = {0.f, 0.f, 0.f, 0.f};
    for (int kc = 0; kc < K; kc += 32) {
        short8 a = *(const short8*)&A[(size_t)(row0 + m) * K + kc + q * 8];
        #pragma unroll
        for (int nt = 0; nt < 16; ++nt) {
            short8 b = *(const short8*)&Wt[(size_t)(nt * 16 + m) * K + kc + q * 8];
            acc[nt] = __builtin_amdgcn_mfma_f32_16x16x32_bf16(a, b, acc[nt], 0, 0, 0);
        }
    }
    #pragma unroll
    for (int nt = 0; nt < 16; ++nt) {
        #pragma unroll
        for (int r = 0; r < 4; ++r)
            outb[(size_t)(row0 + q * 4 + r) * 256 + nt * 16 + m] = f2b(acc[nt][r]);
    }
    float sh_s[4][4] = {{0}}, sh_d[4][4] = {{0}};
    #pragma unroll
    for (int nt = 0; nt < 16; ++nt) {
        int h = nt >> 2;
        int cc = (nt & 3) * 16 + m;
        float asw = att_s_w[h * 64 + cc];
        float adw = att_d_w[h * 64 + cc];
        #pragma unroll
        for (int r = 0; r < 4; ++r) {
            sh_s[h][r] += acc[nt][r] * asw;
            sh_d[h][r] += acc[nt][r] * adw;
        }
    }
    #pragma unroll
    for (int off = 1; off < 16; off <<= 1) {
        #pragma unroll
        for (int h = 0; h < 4; ++h)
            #pragma unroll
            for (int r = 0; r < 4; ++r) {
                sh_s[h][r] += __shfl_xor(sh_s[h][r], off, 64);
                sh_d[h][r] += __shfl_xor(sh_d[h][r], off, 64);
            }
    }
    if (m == 0) {
        #pragma unroll
        for (int r = 0; r < 4; ++r) {
            int row = row0 + q * 4 + r;
            float4 vs = {sh_s[0][r], sh_s[1][r], sh_s[2][r], sh_s[3][r]};
            float4 vd = {sh_d[0][r], sh_d[1][r], sh_d[2][r], sh_d[3][r]};
            *(float4*)&a_s[(size_t)row * 4] = vs;
            *(float4*)&a_d[(size_t)row * 4] = vd;
        }
    }
}

// ---------------- GAT aggregation: pass-2 chunk-4 MLP unroll, NAMED scalars only ------
__global__ __launch_bounds__(256) void k_agg(const u16* __restrict__ xlb,
        const float* __restrict__ a_s, const float* __restrict__ a_d,
        const int* __restrict__ row_ptr, const int* __restrict__ col_src,
        const float* __restrict__ bias, u16* __restrict__ gb_out) {
    int wave = threadIdx.x >> 6, lane = threadIdx.x & 63;
    int dst = blockIdx.x * 2 + (wave >> 1);
    int bp = (wave & 1) * 2;
    int beg = row_ptr[dst], end = row_ptr[dst + 1];

    // pass 1: exact max per (b,h); 8-way edge split across replica groups
    int c = lane & 7, g = lane >> 3;
    int bc = bp + (c >> 2), hc = c & 3;
    float adv1 = a_d[(size_t)dst * 16 + bc * 4 + hc];
    float mloc = -INFINITY;
    for (int i = beg + g; i < end; i += 8) {
        int src = min(max(col_src[i], 0), NNODE - 1);
        float e = a_s[(size_t)src * 16 + bc * 4 + hc] + adv1;
        e = (e >= 0.f) ? e : 0.2f * e;
        mloc = fmaxf(mloc, e);
    }
    mloc = fmaxf(mloc, __shfl_xor(mloc, 8, 64));
    mloc = fmaxf(mloc, __shfl_xor(mloc, 16, 64));
    mloc = fmaxf(mloc, __shfl_xor(mloc, 32, 64));

    int bl = lane >> 5;
    int s = lane & 31;
    int h = s >> 3;
    int b = bp + bl;
    float mv = __shfl(mloc, bl * 4 + h, 64);

    // pass 2: chunk-4 unroll — 4 col_src (contiguous) + 4 a_s + 4 xlb loads in flight.
    float advh = a_d[(size_t)dst * 16 + b * 4 + h];
    float acc[8];
    #pragma unroll
    for (int k = 0; k < 8; ++k) acc[k] = 0.f;
    float l = 0.f;

    int asoff = b * 4 + h;
    int i = beg;
    for (; i + 4 <= end; i += 4) {
        int s0 = min(max(col_src[i], 0), NNODE - 1);
        int s1 = min(max(col_src[i + 1], 0), NNODE - 1);
        int s2 = min(max(col_src[i + 2], 0), NNODE - 1);
        int s3 = min(max(col_src[i + 3], 0), NNODE - 1);
        float a0 = a_s[(size_t)s0 * 16 + asoff];
        float a1 = a_s[(size_t)s1 * 16 + asoff];
        float a2 = a_s[(size_t)s2 * 16 + asoff];
        float a3 = a_s[(size_t)s3 * 16 + asoff];
        short8 x0 = *(const short8*)&xlb[((size_t)s0 * 4 + b) * 256 + s * 8];
        short8 x1 = *(const short8*)&xlb[((size_t)s1 * 4 + b) * 256 + s * 8];
        short8 x2 = *(const short8*)&xlb[((size_t)s2 * 4 + b) * 256 + s * 8];
        short8 x3 = *(const short8*)&xlb[((size_t)s3 * 4 + b) * 256 + s * 8];
        float e0 = a0 + advh; e0 = (e0 >= 0.f) ? e0 : 0.2f * e0;
        float p0 = __expf(e0 - mv); l += p0;
        #pragma unroll
        for (int k = 0; k < 8; ++k) acc[k] += p0 * u2f((u16)x0[k]);
        float e1 = a1 + advh; e1 = (e1 >= 0.f) ? e1 : 0.2f * e1;
        float p1 = __expf(e1 - mv); l += p1;
        #pragma unroll
        for (int k = 0; k < 8; ++k) acc[k] += p1 * u2f((u16)x1[k]);
        float e2 = a2 + advh; e2 = (e2 >= 0.f) ? e2 : 0.2f * e2;
        float p2 = __expf(e2 - mv); l += p2;
        #pragma unroll
        for (int k = 0; k < 8; ++k) acc[k] += p2 * u2f((u16)x2[k]);
        float e3 = a3 + advh; e3 = (e3 >= 0.f) ? e3 : 0.2f * e3;
        float p3 = __expf(e3 - mv); l += p3;
        #pragma unroll
        for (int k = 0; k < 8; ++k) acc[k] += p3 * u2f((u16)x3[k]);
    }
    for (; i < end; ++i) {
        int s0 = min(max(col_src[i], 0), NNODE - 1);
        float a0 = a_s[(size_t)s0 * 16 + asoff];
        short8 x0 = *(const short8*)&xlb[((size_t)s0 * 4 + b) * 256 + s * 8];
        float e0 = a0 + advh; e0 = (e0 >= 0.f) ? e0 : 0.2f * e0;
        float p0 = __expf(e0 - mv); l += p0;
        #pragma unroll
        for (int k = 0; k < 8; ++k) acc[k] += p0 * u2f((u16)x0[k]);
    }
    float rl = 1.f / (l + 1e-16f);
    short8 o;
    #pragma unroll
    for (int k = 0; k < 8; ++k)
        o[k] = (short)f2b(prelu(acc[k] * rl + bias[s * 8 + k]));
    *(short8*)&gb_out[((size_t)dst * 4 + b) * 256 + s * 8] = o;
}

// ---------------- attribution head (blocks <625) + pooled sum (blocks >=625) ----------
__global__ __launch_bounds__(256) void k_attrpool(const u16* __restrict__ gb,
        const u16* __restrict__ Wa1t, const float* __restrict__ wbuf,
        float* __restrict__ out, float* __restrict__ pooled) {
    if (blockIdx.x >= 625) {   // pool part, n-loop unrolled x4 (independent loads)
        int pb = blockIdx.x - 625;
        int b = pb >> 6;
        int chunk = pb & 63;
        int cch = threadIdx.x;
        int n0 = chunk * 157;
        int n1 = min(NNODE, n0 + 157);
        float acc = 0.f;
        int n = n0;
        for (; n + 4 <= n1; n += 4) {
            float v0 = u2f(gb[((size_t)n * 4 + b) * 256 + cch]);
            float v1 = u2f(gb[((size_t)(n + 1) * 4 + b) * 256 + cch]);
            float v2 = u2f(gb[((size_t)(n + 2) * 4 + b) * 256 + cch]);
            float v3 = u2f(gb[((size_t)(n + 3) * 4 + b) * 256 + cch]);
            acc += v0; acc += v1; acc += v2; acc += v3;
        }
        for (; n < n1; ++n)
            acc += u2f(gb[((size_t)n * 4 + b) * 256 + cch]);
        atomicAdd(&pooled[b * 256 + cch], acc);
        return;
    }
    int wave = threadIdx.x >> 6, lane = threadIdx.x & 63;
    int row0 = (blockIdx.x * 4 + wave) * 16;
    int m = lane & 15, q = lane >> 4;
    f32x4 acc[4];
    #pragma unroll
    for (int nt = 0; nt < 4; ++nt) acc[nt] = {0.f, 0.f, 0.f, 0.f};
    for (int kc = 0; kc < 256; kc += 32) {
        short8 a = *(const short8*)&gb[(size_t)(row0 + m) * 256 + kc + q * 8];
        #pragma unroll
        for (int nt = 0; nt < 4; ++nt) {
            short8 b = *(const short8*)&Wa1t[(size_t)(nt * 16 + m) * 256 + kc + q * 8];
            acc[nt] = __builtin_amdgcn_mfma_f32_16x16x32_bf16(a, b, acc[nt], 0, 0, 0);
        }
    }
    float part[4] = {0, 0, 0, 0};
    #pragma unroll
    for (int nt = 0; nt < 4; ++nt) {
        int col = nt * 16 + m;
        float ba1v = wbuf[S_BA1 + col];
        float wa2v = wbuf[S_WA2 + col];
        #pragma unroll
        for (int r = 0; r < 4; ++r)
            part[r] += prelu(acc[nt][r] + ba1v) * wa2v;
    }
    #pragma unroll
    for (int off = 1; off < 16; off <<= 1) {
        #pragma unroll
        for (int r = 0; r < 4; ++r)
            part[r] += __shfl_xor(part[r], off, 64);
    }
    if (m == 0) {
        float ba2v = wbuf[S_BA2];
        #pragma unroll
        for (int r = 0; r < 4; ++r) {
            int row = row0 + q * 4 + r;
            int n = row >> 2, b = row & 3;
            float v = part[r] + ba2v;
            out[8 + b * NNODE + n] = 1.f / (1.f + __expf(-v));
        }
    }
}

// ---------------- classification head (blocks 0-3) + diagnostics (block 4) ----------
__global__ __launch_bounds__(128) void k_logits(const float* __restrict__ pooled,
        const float* __restrict__ wbuf, const void* __restrict__ Wc1p,
        float* __restrict__ out,
        const u16* __restrict__ featb, const u16* __restrict__ gb,
        const int* __restrict__ row_ptr, const int* __restrict__ ei,
        const void* __restrict__ xsrc, int hostbad) {
    int tid = threadIdx.x;
    bool isbf = probe_x_bf16(xsrc);
    if (blockIdx.x == 4) {   // sampled diagnostics
        __shared__ float red[128];
        bool ei64 = probe_ei64(ei);
        float mx[2] = {0.f, 0.f};
        const u16* bufs[2] = {featb, gb};
        for (int qq = 0; qq < 2; ++qq) {
            const u16* p = bufs[qq];
            float m = 0.f;
            for (int i = tid; i < 2048; i += 128) {
                float v = u2f(p[i]);
                if (v != v) m = 1e30f;
                m = fmaxf(m, fabsf(v));
            }
            red[tid] = m;
            __syncthreads();
            for (int s2 = 64; s2 > 0; s2 >>= 1) {
                if (tid < s2) red[tid] = fmaxf(red[tid], red[tid + s2]);
                __syncthreads();
            }
            mx[qq] = red[0];
            __syncthreads();
        }
        if (tid == 0) {
            int fb = (mx[0] > 1e8f || mx[0] < 1e-6f) ? 1 : 0;
            int gbad = (mx[1] > 1e8f || mx[1] < 1e-6f) ? 1 : 0;
            int cb = (row_ptr[NNODE] != NEDGE + NNODE) ? 1 : 0;
            int code = 100 * fb + 400 * gbad + 800 * cb + 6400 * hostbad;
            if (code) {
                code += 1600 * (isbf ? 0 : 1);
                code += 3200 * (ei64 ? 1 : 0);
                for (int j = 0; j < 8; ++j) out[j] = (float)code;
            }
        }
        return;
    }
    __shared__ float pm[256];
    __shared__ float red4[4];
    int b = blockIdx.x;
    pm[tid] = pooled[b * 256 + tid] * (1.f / NNODE);
    pm[tid + 128] = pooled[b * 256 + tid + 128] * (1.f / NNODE);
    __syncthreads();
    float acc = wbuf[S_BC1 + tid];
    if (isbf) {
        const u16* w = (const u16*)Wc1p;
        #pragma unroll 4
        for (int k = 0; k < 256; ++k)
            acc += pm[k] * u2f(w[k * 128 + tid]);
    } else {
        const float* w = (const float*)Wc1p;
        #pragma unroll 4
        for (int k = 0; k < 256; ++k)
            acc += pm[k] * w[k * 128 + tid];
    }
    float hv = prelu(acc);
    float p0 = hv * wbuf[S_WC2 + tid * 2];
    float p1 = hv * wbuf[S_WC2 + tid * 2 + 1];
    #pragma unroll
    for (int off = 32; off > 0; off >>= 1) {
        p0 += __shfl_xor(p0, off, 64);
        p1 += __shfl_xor(p1, off, 64);
    }
    int wv = tid >> 6, lane = tid & 63;
    if (lane == 0) { red4[wv * 2] = p0; red4[wv * 2 + 1] = p1; }
    __syncthreads();
    if (tid < 2)
        out[b * 2 + tid] = red4[tid] + red4[2 + tid] + wbuf[S_BC2 + tid];
}

extern "C" void kernel_launch(void* const* d_in, const int* in_sizes, int n_in,
                              void* d_out, int out_size, void* d_ws, size_t ws_size,
                              hipStream_t stream) {
    const void* x  = d_in[0];
    const int*  ei = (const int*)d_in[1];
    float* out = (float*)d_out;

    WPtrs wp;
    for (int j = 0; j < 20; ++j) wp.p[j] = d_in[j + 2];

    char* ws = (char*)d_ws;
    size_t off = 0;
    auto alloc = [&](size_t bytes) -> void* {
        void* p = ws + off;
        off += (bytes + 255) & ~(size_t)255;
        return p;
    };
    float* wbuf    = (float*)alloc((size_t)S_TOTAL * 4);
    u16*   featb   = (u16*)  alloc((size_t)BATCH * NNODE * 64 * 2);
    u16*   xlb     = (u16*)  alloc((size_t)BATCH * NNODE * 256 * 2);
    u16*   gb      = (u16*)  alloc((size_t)BATCH * NNODE * 256 * 2);
    float* a_s     = (float*)alloc((size_t)BATCH * NNODE * 4 * 4);
    float* a_d     = (float*)alloc((size_t)BATCH * NNODE * 4 * 4);
    u16*   cw2r    = (u16*)alloc(6144 * 2);
    u16*   W0t     = (u16*)alloc(16384 * 2);
    u16*   W1t     = (u16*)alloc(65536 * 2);
    u16*   Wa1t    = (u16*)alloc(16384 * 2);
    // counts and pooled ADJACENT: one memset zeroes both
    int*   counts  = (int*)alloc(NNODE * 4);           // padded to 40192
    float* pooled  = (float*)alloc(BATCH * 256 * 4);   // 4096
    int*   row_ptr = (int*)alloc((NNODE + 1) * 4);
    int*   cur     = (int*)alloc(NNODE * 4);
    int*   col_src = (int*)alloc((NEDGE + NNODE) * 4);
    int*   bsum    = (int*)alloc(64 * 4);
    (void)ws_size; (void)out_size;

    int hostbad = (n_in != 22 || in_sizes[0] != BATCH * NNODE * TLEN ||
                   in_sizes[1] != 2 * NEDGE) ? 1 : 0;

    hipMemsetAsync(counts, 0, 40192 + 4096, stream);

    k_pre<<<PRE_TBLK + 9, 256, 0, stream>>>(wp, x, ei, wbuf, cw2r, W0t, W1t, Wa1t, counts);
    k_scan1<<<40, 256, 0, stream>>>(counts, cur, bsum);
    k_scan3<<<40, 256, 0, stream>>>(counts, cur, bsum, row_ptr);

    // conv + CSR fill fused
    k_conv<<<BATCH * NNODE / 4, 256, 0, stream>>>(x, wbuf, cw2r, featb, ei, cur, col_src);

    // GAT layer 0
    k_gemm<64><<<BATCH * NNODE / 64, 256, 0, stream>>>(featb, W0t,
            wbuf + S_AS0, wbuf + S_AD0, xlb, a_s, a_d);
    k_agg<<<NNODE / 2, 256, 0, stream>>>(xlb, a_s, a_d, row_ptr, col_src, wbuf + S_B0, gb);

    // GAT layer 1
    k_gemm<256><<<BATCH * NNODE / 64, 256, 0, stream>>>(gb, W1t,
            wbuf + S_AS1, wbuf + S_AD1, xlb, a_s, a_d);
    k_agg<<<NNODE / 2, 256, 0, stream>>>(xlb, a_s, a_d, row_ptr, col_src, wbuf + S_B1, gb);

    // heads
    k_attrpool<<<625 + 256, 256, 0, stream>>>(gb, Wa1t, wbuf, out, pooled);
    k_logits<<<5, 128, 0, stream>>>(pooled, wbuf, wp.p[12], out, featb, gb, row_ptr, ei, x, hostbad);
}